// Round 11
// baseline (503.733 us; speedup 1.0000x reference)
//
#include <hip/hip_runtime.h>
#include <hip/hip_bf16.h>
#include <hip/hip_cooperative_groups.h>

namespace cg = cooperative_groups;

// Problem constants
#define B_  64
#define C_  64
#define T_  300
#define V_  25
#define O_  128
#define TV  (T_*V_)     // 7500
#define BTV (B_*T_*V_)  // 480000
#define HS_STRIDE 258   // LDS H row stride (shorts): conflict-free gather
#define HS_ROWS 107
#define NBLK 480        // cooperative grid (2 blocks/CU guaranteed)
#define TILES_PB 10     // 4800 tiles / 480 blocks

typedef __bf16 bf16x8 __attribute__((ext_vector_type(8)));
typedef float f32x4 __attribute__((ext_vector_type(4)));

// ---- ws layout (byte offsets) ----
#define WSB_AF    0ull           // A-fragment table [18][64][8] bf16 = 18432
#define WSB_WT    18432ull       // Wt[256][64] bf16 = 32768 -> 51200
#define WSB_PSC   51200ull       // [4800][128] f32 slot (mega uses [480][128])
#define WSB_PSQ   2508800ull
#define WSB_P2C   4966400ull
#define WSB_P2Q   5015552ull
#define WSB_SCL   5064704ull
#define WSB_SFT   5065216ull
#define WSB_Y     5065728ull     // fallback Y [B*128][7500] bf16
#define WS_NEED2  127945728ull

static __device__ __forceinline__ unsigned short f2bf(float f) {
    unsigned int u = __float_as_uint(f);
    unsigned int r = (u + 0x7fffu + ((u >> 16) & 1u)) >> 16;
    return (unsigned short)r;
}
static __device__ __forceinline__ float bf2f(unsigned short u) {
    return __uint_as_float(((unsigned int)u) << 16);
}

// ---------------- prep: block 0 = A-power MFMA fragment table; block 1 = Wt ----
__global__ __launch_bounds__(256) void k_prep(const float* __restrict__ A,
                                              const float* __restrict__ W,
                                              const float* __restrict__ Wr,
                                              unsigned short* __restrict__ AF,
                                              unsigned short* __restrict__ Wt) {
    const int tid = threadIdx.x;
    if (blockIdx.x == 0) {
        __shared__ float Pall[8][625];
        for (int p = tid; p < 625; p += 256) Pall[0][p] = A[p];
        __syncthreads();
        for (int i = 1; i < 8; i++) {
            for (int p = tid; p < 625; p += 256) {
                int r = p / 25, c = p - r * 25;
                float s = 0.f;
                #pragma unroll 5
                for (int j = 0; j < 25; j++) s = fmaf(Pall[i-1][r*25 + j], A[j*25 + c], s);
                Pall[i][p] = s;
            }
            __syncthreads();
        }
        for (int idx = tid; idx < 18 * 64; idx += 256) {
            int fi = idx >> 6, l = idx & 63, qq = l >> 4, tt = l & 15;
            unsigned short v[8];
            #pragma unroll
            for (int e = 0; e < 8; e++) {
                int j = qq * 8 + e;
                float val = 0.f;
                if (fi < 16) {
                    int i = fi >> 1, k = (fi & 1) * 16 + tt;
                    if (j < 25 && k < 25) val = Pall[i][j * 25 + k];
                } else {
                    int k = (fi - 16) * 16 + tt;
                    if (j < 25 && k < 25 && j == k) val = 1.f;
                }
                v[e] = f2bf(val);
            }
            *(uint4*)(AF + idx * 8) = *(uint4*)v;
        }
    } else {
        const int oc = tid;
        const float* src = (oc < 128) ? (W + oc * 64) : (Wr + (oc - 128) * 64);
        unsigned short row[64];
        #pragma unroll
        for (int c = 0; c < 64; c++) row[c] = f2bf(src[c]);
        #pragma unroll
        for (int cc = 0; cc < 8; cc++)
            *(uint4*)(Wt + oc * 64 + cc * 8) = *(uint4*)(row + cc * 8);
    }
}

// ---------------- cooperative mega-kernel: everything after prep ----------------
__global__ __launch_bounds__(512, 4) void k_mega(const float* __restrict__ x,
                                                 const unsigned short* __restrict__ Wt,
                                                 const unsigned short* __restrict__ AF,
                                                 const float* __restrict__ gamma,
                                                 const float* __restrict__ beta,
                                                 float* __restrict__ psc,
                                                 float* __restrict__ psq,
                                                 float* __restrict__ out) {
    __shared__ __align__(16) unsigned short SM[8192 + HS_ROWS * HS_STRIDE];
    __shared__ float scl[128], sft[128];
    unsigned short* As = SM;
    unsigned short* Hs = SM + 8192;
    const int tid = threadIdx.x, wv = tid >> 6, ln = tid & 63;
    const int q = ln >> 4, t = ln & 15;
    const int s = wv >> 1, bh = wv & 1;
    const bf16x8* AFp = (const bf16x8*)AF;
    const bf16x8 id0 = AFp[16 * 64 + ln];
    const bf16x8 id1 = AFp[17 * 64 + ln];
    const int tile0 = blockIdx.x * TILES_PB;

    // one-time zero of pad rows (stay zero across tiles)
    for (int w = tid; w < 896; w += 512) ((unsigned int*)As)[3200 + w] = 0u;   // As rows 100..127
    for (int w = tid; w < 903; w += 512) ((unsigned int*)Hs)[12900 + w] = 0u;  // Hs rows 100..106

    float sacc[4] = {0.f, 0.f, 0.f, 0.f}, qacc[4] = {0.f, 0.f, 0.f, 0.f};
    uint2 y[TILES_PB][4][2];

    #pragma unroll
    for (int tl = 0; tl < TILES_PB; tl++) {
        const int tile = tile0 + tl;
        const int b = tile / 75, tg = tile - b * 75;
        __syncthreads();   // prior phase-1 As reads & phase-2 Hs reads done
        // stage x -> As bf16 [row 0..99][c], chunk-XOR swizzled by row&7
        for (int p = tid; p < 1600; p += 512) {
            int c = p / 25, e4 = p - c * 25;
            float4 f = *(const float4*)(x + ((size_t)(b * 64 + c)) * TV + tg * 100 + e4 * 4);
            float vv[4] = { f.x, f.y, f.z, f.w };
            #pragma unroll
            for (int u = 0; u < 4; u++) {
                int r = e4 * 4 + u;
                As[r * 64 + (((c >> 3) ^ (r & 7)) << 3) + (c & 7)] = f2bf(vv[u]);
            }
        }
        __syncthreads();
        // phase 1: H[128][256] = As . Wt^T ; wave = (rowblock rb, oc-quad oq)
        {
            const int rb = wv >> 2, oq = wv & 3;
            f32x4 acc[4][4] = {};
            #pragma unroll
            for (int ks = 0; ks < 2; ks++) {
                const unsigned short* wb = Wt + (oq * 64 + t) * 64 + q * 8 + ks * 32;
                bf16x8 bv[4], af[4];
                #pragma unroll
                for (int ni = 0; ni < 4; ni++) bv[ni] = *(const bf16x8*)(wb + ni * 1024);
                #pragma unroll
                for (int mi = 0; mi < 4; mi++) {
                    int row = rb * 64 + mi * 16 + t;
                    af[mi] = *(const bf16x8*)(As + row * 64 + (((ks * 4 + q) ^ (row & 7)) << 3));
                }
                #pragma unroll
                for (int mi = 0; mi < 4; mi++)
                    #pragma unroll
                    for (int ni = 0; ni < 4; ni++)
                        acc[mi][ni] = __builtin_amdgcn_mfma_f32_16x16x32_bf16(bv[ni], af[mi], acc[mi][ni], 0, 0, 0);
            }
            #pragma unroll
            for (int mi = 0; mi < 4; mi++) {
                int row = rb * 64 + mi * 16 + t;
                if (row < 100) {
                    #pragma unroll
                    for (int ni = 0; ni < 4; ni++) {
                        int co = oq * 64 + ni * 16 + q * 4;
                        unsigned int* dst = (unsigned int*)(Hs + row * HS_STRIDE + co);
                        dst[0] = (unsigned int)f2bf(acc[mi][ni][0]) | ((unsigned int)f2bf(acc[mi][ni][1]) << 16);
                        dst[1] = (unsigned int)f2bf(acc[mi][ni][2]) | ((unsigned int)f2bf(acc[mi][ni][3]) << 16);
                    }
                }
            }
        }
        __syncthreads();
        // phase 2: wave = (slab s, branch-half bh); results -> y regs + stats regs
        {
            f32x4 acc2[4][2];
            #pragma unroll
            for (int ii = 0; ii < 4; ii++) { acc2[ii][0] = (f32x4){0,0,0,0}; acc2[ii][1] = (f32x4){0,0,0,0}; }
            const int rowq = (s * 25 + q * 8) * HS_STRIDE + t;
            #pragma unroll
            for (int ii = 0; ii < 4; ii++) {
                const int i = bh * 4 + ii;
                unsigned short hm[8], hr[8];
                #pragma unroll
                for (int e = 0; e < 8; e++) {
                    int a = rowq + e * HS_STRIDE + i * 16;
                    hm[e] = Hs[a];
                    hr[e] = Hs[a + 128];
                }
                bf16x8 bm = *(bf16x8*)hm;
                bf16x8 brs = *(bf16x8*)hr;
                bf16x8 a0 = AFp[(i * 2 + 0) * 64 + ln];
                bf16x8 a1 = AFp[(i * 2 + 1) * 64 + ln];
                acc2[ii][0] = __builtin_amdgcn_mfma_f32_16x16x32_bf16(id0, brs, acc2[ii][0], 0, 0, 0);
                acc2[ii][1] = __builtin_amdgcn_mfma_f32_16x16x32_bf16(id1, brs, acc2[ii][1], 0, 0, 0);
                acc2[ii][0] = __builtin_amdgcn_mfma_f32_16x16x32_bf16(a0, bm, acc2[ii][0], 0, 0, 0);
                acc2[ii][1] = __builtin_amdgcn_mfma_f32_16x16x32_bf16(a1, bm, acc2[ii][1], 0, 0, 0);
            }
            #pragma unroll
            for (int ii = 0; ii < 4; ii++) {
                float si = 0.f, qi = 0.f;
                #pragma unroll
                for (int mt = 0; mt < 2; mt++) {
                    #pragma unroll
                    for (int r = 0; r < 4; r++) {
                        float v = acc2[ii][mt][r];
                        si += v; qi += v * v;
                    }
                    y[tl][ii][mt].x = (unsigned int)f2bf(acc2[ii][mt][0]) | ((unsigned int)f2bf(acc2[ii][mt][1]) << 16);
                    y[tl][ii][mt].y = (unsigned int)f2bf(acc2[ii][mt][2]) | ((unsigned int)f2bf(acc2[ii][mt][3]) << 16);
                }
                sacc[ii] += si; qacc[ii] += qi;
            }
        }
    }

    // block-level BN partials -> global
    __syncthreads();
    float* ps = (float*)SM;    // As region dead
    float* qs = ps + 512;
    #pragma unroll
    for (int ii = 0; ii < 4; ii++) {
        float si = sacc[ii], qi = qacc[ii];
        si += __shfl_xor(si, 16); si += __shfl_xor(si, 32);
        qi += __shfl_xor(qi, 16); qi += __shfl_xor(qi, 32);
        if (ln < 16) {
            ps[s * 128 + (bh * 4 + ii) * 16 + t] = si;
            qs[s * 128 + (bh * 4 + ii) * 16 + t] = qi;
        }
    }
    __syncthreads();
    if (tid < 128) {
        psc[blockIdx.x * 128 + tid] = ps[tid] + ps[128 + tid] + ps[256 + tid] + ps[384 + tid];
        psq[blockIdx.x * 128 + tid] = qs[tid] + qs[128 + tid] + qs[256 + tid] + qs[384 + tid];
    }

    cg::this_grid().sync();

    // every block redundantly reduces the (L2-resident) partials -> scale/shift
    {
        const int o = tid & 127, ph = tid >> 7;
        float S = 0.f, Q = 0.f;
        for (int i = ph; i < NBLK; i += 4) {
            S += psc[i * 128 + o];
            Q += psq[i * 128 + o];
        }
        ps[ph * 128 + o] = S;
        qs[ph * 128 + o] = Q;
        __syncthreads();
        if (tid < 128) {
            float St = ps[tid] + ps[128 + tid] + ps[256 + tid] + ps[384 + tid];
            float Qt = qs[tid] + qs[128 + tid] + qs[256 + tid] + qs[384 + tid];
            float inv = 1.f / (float)BTV;
            float mean = St * inv;
            float var = Qt * inv - mean * mean;
            float sc = gamma[tid] / sqrtf(var + 1e-5f);
            scl[tid] = sc;
            sft[tid] = beta[tid] - mean * sc;
        }
    }

    // output: per tile, y regs -> Hs -> normalized float4 writes
    #pragma unroll
    for (int tl = 0; tl < TILES_PB; tl++) {
        const int tile = tile0 + tl;
        const int b = tile / 75, tg = tile - b * 75;
        __syncthreads();   // prior tile's Hs reads done (and initial scl/sft ready)
        #pragma unroll
        for (int ii = 0; ii < 4; ii++)
            #pragma unroll
            for (int mt = 0; mt < 2; mt++) {
                unsigned int lo = y[tl][ii][mt].x, hi = y[tl][ii][mt].y;
                unsigned short vr[4] = { (unsigned short)(lo & 0xffffu), (unsigned short)(lo >> 16),
                                         (unsigned short)(hi & 0xffffu), (unsigned short)(hi >> 16) };
                #pragma unroll
                for (int r = 0; r < 4; r++) {
                    int k = mt * 16 + q * 4 + r;
                    if (k < 25)
                        Hs[(s * 25 + k) * HS_STRIDE + (bh * 4 + ii) * 16 + t] = vr[r];
                }
            }
        __syncthreads();
        for (int idx = tid; idx < 3200; idx += 512) {
            int o = idx / 25, w = idx - o * 25;
            float sc = scl[o], sh = sft[o];
            float4 d;
            float* dp = (float*)&d;
            #pragma unroll
            for (int e = 0; e < 4; e++)
                dp[e] = fmaxf(fmaf(bf2f(Hs[(w * 4 + e) * HS_STRIDE + o]), sc, sh), 0.f);
            *(float4*)(out + (size_t)(b * 128 + o) * TV + tg * 100 + w * 4) = d;
        }
    }
}

// =================== FALLBACK: exact round-10 path ===================
__global__ __launch_bounds__(512, 2) void k_fuse(const float* __restrict__ x,
                                                 const unsigned short* __restrict__ Wt,
                                                 const unsigned short* __restrict__ AF,
                                                 unsigned short* __restrict__ Yg,
                                                 float* __restrict__ psc,
                                                 float* __restrict__ psq) {
    __shared__ __align__(16) unsigned short SM[8192 + HS_ROWS * HS_STRIDE];
    unsigned short* As = SM;
    unsigned short* Hs = SM + 8192;
    const int tg = blockIdx.x, b = blockIdx.y;
    const int tid = threadIdx.x, wv = tid >> 6, ln = tid & 63;
    const int q = ln >> 4, t = ln & 15;

    for (int p = tid; p < 1600; p += 512) {
        int c = p / 25, e4 = p - c * 25;
        float4 f = *(const float4*)(x + ((size_t)(b * 64 + c)) * TV + tg * 100 + e4 * 4);
        float vv[4] = { f.x, f.y, f.z, f.w };
        #pragma unroll
        for (int u = 0; u < 4; u++) {
            int r = e4 * 4 + u;
            As[r * 64 + (((c >> 3) ^ (r & 7)) << 3) + (c & 7)] = f2bf(vv[u]);
        }
    }
    for (int w = tid; w < 896; w += 512) ((unsigned int*)As)[3200 + w] = 0u;
    for (int w = tid; w < 903; w += 512) ((unsigned int*)Hs)[12900 + w] = 0u;
    __syncthreads();
    {
        const int rb = wv >> 2, oq = wv & 3;
        f32x4 acc[4][4] = {};
        #pragma unroll
        for (int ks = 0; ks < 2; ks++) {
            const unsigned short* wb = Wt + (oq * 64 + t) * 64 + q * 8 + ks * 32;
            bf16x8 bv[4], af[4];
            #pragma unroll
            for (int ni = 0; ni < 4; ni++) bv[ni] = *(const bf16x8*)(wb + ni * 1024);
            #pragma unroll
            for (int mi = 0; mi < 4; mi++) {
                int row = rb * 64 + mi * 16 + t;
                af[mi] = *(const bf16x8*)(As + row * 64 + (((ks * 4 + q) ^ (row & 7)) << 3));
            }
            #pragma unroll
            for (int mi = 0; mi < 4; mi++)
                #pragma unroll
                for (int ni = 0; ni < 4; ni++)
                    acc[mi][ni] = __builtin_amdgcn_mfma_f32_16x16x32_bf16(bv[ni], af[mi], acc[mi][ni], 0, 0, 0);
        }
        #pragma unroll
        for (int mi = 0; mi < 4; mi++) {
            int row = rb * 64 + mi * 16 + t;
            if (row < 100) {
                #pragma unroll
                for (int ni = 0; ni < 4; ni++) {
                    int co = oq * 64 + ni * 16 + q * 4;
                    unsigned int* dst = (unsigned int*)(Hs + row * HS_STRIDE + co);
                    dst[0] = (unsigned int)f2bf(acc[mi][ni][0]) | ((unsigned int)f2bf(acc[mi][ni][1]) << 16);
                    dst[1] = (unsigned int)f2bf(acc[mi][ni][2]) | ((unsigned int)f2bf(acc[mi][ni][3]) << 16);
                }
            }
        }
    }
    __syncthreads();
    const int s = wv >> 1, bh = wv & 1;
    const bf16x8* AFp = (const bf16x8*)AF;
    const bf16x8 id0 = AFp[16 * 64 + ln];
    const bf16x8 id1 = AFp[17 * 64 + ln];
    f32x4 acc2[4][2];
    #pragma unroll
    for (int ii = 0; ii < 4; ii++) { acc2[ii][0] = (f32x4){0,0,0,0}; acc2[ii][1] = (f32x4){0,0,0,0}; }
    const int rowq = (s * 25 + q * 8) * HS_STRIDE + t;
    #pragma unroll
    for (int ii = 0; ii < 4; ii++) {
        const int i = bh * 4 + ii;
        unsigned short hm[8], hr[8];
        #pragma unroll
        for (int e = 0; e < 8; e++) {
            int a = rowq + e * HS_STRIDE + i * 16;
            hm[e] = Hs[a];
            hr[e] = Hs[a + 128];
        }
        bf16x8 bm = *(bf16x8*)hm;
        bf16x8 brs = *(bf16x8*)hr;
        bf16x8 a0 = AFp[(i * 2 + 0) * 64 + ln];
        bf16x8 a1 = AFp[(i * 2 + 1) * 64 + ln];
        acc2[ii][0] = __builtin_amdgcn_mfma_f32_16x16x32_bf16(id0, brs, acc2[ii][0], 0, 0, 0);
        acc2[ii][1] = __builtin_amdgcn_mfma_f32_16x16x32_bf16(id1, brs, acc2[ii][1], 0, 0, 0);
        acc2[ii][0] = __builtin_amdgcn_mfma_f32_16x16x32_bf16(a0, bm, acc2[ii][0], 0, 0, 0);
        acc2[ii][1] = __builtin_amdgcn_mfma_f32_16x16x32_bf16(a1, bm, acc2[ii][1], 0, 0, 0);
    }
    float* ps = (float*)SM;
    float* qs = ps + 512;
    #pragma unroll
    for (int ii = 0; ii < 4; ii++) {
        float si = 0.f, qi = 0.f;
        #pragma unroll
        for (int mt = 0; mt < 2; mt++)
            #pragma unroll
            for (int r = 0; r < 4; r++) {
                float v = acc2[ii][mt][r];
                si += v; qi += v * v;
            }
        si += __shfl_xor(si, 16); si += __shfl_xor(si, 32);
        qi += __shfl_xor(qi, 16); qi += __shfl_xor(qi, 32);
        if (ln < 16) {
            ps[s * 128 + (bh * 4 + ii) * 16 + t] = si;
            qs[s * 128 + (bh * 4 + ii) * 16 + t] = qi;
        }
    }
    #pragma unroll
    for (int ii = 0; ii < 4; ii++)
        #pragma unroll
        for (int mt = 0; mt < 2; mt++)
            #pragma unroll
            for (int r = 0; r < 4; r++) {
                int k = mt * 16 + q * 4 + r;
                if (k < 25)
                    Hs[(s * 25 + k) * HS_STRIDE + (bh * 4 + ii) * 16 + t] = f2bf(acc2[ii][mt][r]);
            }
    __syncthreads();
    if (tid < 128) {
        float S = ps[tid] + ps[128 + tid] + ps[256 + tid] + ps[384 + tid];
        float Q = qs[tid] + qs[128 + tid] + qs[256 + tid] + qs[384 + tid];
        int blk = b * 75 + tg;
        psc[(size_t)blk * 128 + tid] = S;
        psq[(size_t)blk * 128 + tid] = Q;
    }
    for (int idx = tid; idx < 3200; idx += 512) {
        int o = idx / 25, w = idx - o * 25;
        unsigned short vv[4];
        #pragma unroll
        for (int e = 0; e < 4; e++)
            vv[e] = Hs[(w * 4 + e) * HS_STRIDE + o];
        uint2 d;
        d.x = (unsigned int)vv[0] | ((unsigned int)vv[1] << 16);
        d.y = (unsigned int)vv[2] | ((unsigned int)vv[3] << 16);
        *(uint2*)(Yg + (size_t)(b * 128 + o) * TV + tg * 100 + w * 4) = d;
    }
}

__global__ __launch_bounds__(256) void k_red1(const float* __restrict__ psc,
                                              const float* __restrict__ psq,
                                              float* __restrict__ p2c,
                                              float* __restrict__ p2q) {
    const int r = blockIdx.x;
    const int tid = threadIdx.x;
    const int o = tid & 127;
    const float* src = (tid < 128) ? psc : psq;
    float* dst = (tid < 128) ? p2c : p2q;
    float S = 0.f;
    for (int ii = 0; ii < 50; ii++)
        S += src[(size_t)(r * 50 + ii) * 128 + o];
    dst[r * 128 + o] = S;
}

__global__ void k_fin(const float* __restrict__ p2c, const float* __restrict__ p2q,
                      const float* __restrict__ gamma, const float* __restrict__ beta,
                      float* __restrict__ scale, float* __restrict__ shift) {
    const int o = threadIdx.x;
    if (o >= 128) return;
    float S = 0.f, Q = 0.f;
    for (int r = 0; r < 96; r++) { S += p2c[r * 128 + o]; Q += p2q[r * 128 + o]; }
    float inv = 1.f / (float)BTV;
    float mean = S * inv;
    float var = Q * inv - mean * mean;
    float sc = gamma[o] / sqrtf(var + 1e-5f);
    scale[o] = sc;
    shift[o] = beta[o] - mean * sc;
}

__global__ __launch_bounds__(256) void k_norm2(const unsigned short* __restrict__ Y,
                                               const float* __restrict__ scale,
                                               const float* __restrict__ shift,
                                               float* __restrict__ out) {
    size_t e0 = ((size_t)blockIdx.x * 256 + threadIdx.x) * 8;
    #pragma unroll
    for (int g = 0; g < 2; g++) {
        size_t e = e0 + (size_t)g * 4;
        int o = (int)((e / 7500) & 127);
        float sc = scale[o], sh = shift[o];
        uint2 v = *(const uint2*)(Y + e);
        float4 d;
        d.x = fmaxf(fmaf(bf2f((unsigned short)(v.x & 0xffffu)), sc, sh), 0.f);
        d.y = fmaxf(fmaf(bf2f((unsigned short)(v.x >> 16)),     sc, sh), 0.f);
        d.z = fmaxf(fmaf(bf2f((unsigned short)(v.y & 0xffffu)), sc, sh), 0.f);
        d.w = fmaxf(fmaf(bf2f((unsigned short)(v.y >> 16)),     sc, sh), 0.f);
        *(float4*)(out + e) = d;
    }
}

extern "C" void kernel_launch(void* const* d_in, const int* in_sizes, int n_in,
                              void* d_out, int out_size, void* d_ws, size_t ws_size,
                              hipStream_t stream) {
    const float* x     = (const float*)d_in[0];
    const float* A     = (const float*)d_in[1];
    const float* W     = (const float*)d_in[2];
    const float* Wr    = (const float*)d_in[3];
    const float* gamma = (const float*)d_in[5];
    const float* beta  = (const float*)d_in[6];
    float* out = (float*)d_out;
    char* wsb  = (char*)d_ws;
    if (ws_size < (size_t)WS_NEED2) return;

    unsigned short* AF  = (unsigned short*)(wsb + WSB_AF);
    unsigned short* Wt  = (unsigned short*)(wsb + WSB_WT);
    float*          psc = (float*)(wsb + WSB_PSC);
    float*          psq = (float*)(wsb + WSB_PSQ);
    float*          p2c = (float*)(wsb + WSB_P2C);
    float*          p2q = (float*)(wsb + WSB_P2Q);
    float*          scl = (float*)(wsb + WSB_SCL);
    float*          sft = (float*)(wsb + WSB_SFT);
    unsigned short* Y   = (unsigned short*)(wsb + WSB_Y);

    k_prep<<<2, 256, 0, stream>>>(A, W, Wr, AF, Wt);

    void* args[] = { (void*)&x, (void*)&Wt, (void*)&AF, (void*)&gamma, (void*)&beta,
                     (void*)&psc, (void*)&psq, (void*)&out };
    hipError_t err = hipLaunchCooperativeKernel((const void*)k_mega, dim3(NBLK), dim3(512),
                                                args, 0, stream);
    if (err != hipSuccess) {
        // fallback: proven round-10 path
        k_fuse<<<dim3(75, 64), 512, 0, stream>>>(x, Wt, AF, Y, psc, psq);
        k_red1<<<96, 256, 0, stream>>>(psc, psq, p2c, p2q);
        k_fin<<<1, 128, 0, stream>>>(p2c, p2q, gamma, beta, scl, sft);
        k_norm2<<<30000, 256, 0, stream>>>(Y, scl, sft, out);
    }
}

// Round 12
// 502.956 us; speedup vs baseline: 1.0015x; 1.0015x over previous
//
#include <hip/hip_runtime.h>
#include <hip/hip_bf16.h>
#include <hip/hip_cooperative_groups.h>

namespace cg = cooperative_groups;

// Problem constants
#define B_  64
#define C_  64
#define T_  300
#define V_  25
#define O_  128
#define TV  (T_*V_)     // 7500
#define BTV (B_*T_*V_)  // 480000
#define NELEM 61440000  // out elements
#define HS_STRIDE 258
#define HS_ROWS 107
#define NBLK 480        // cooperative grid (2 blocks/CU)
#define TILES_PB 10     // 4800 tiles / 480 blocks

typedef __bf16 bf16x8 __attribute__((ext_vector_type(8)));
typedef float f32x4 __attribute__((ext_vector_type(4)));

// ---- ws layout (byte offsets) ----
#define WSB_AF    0ull
#define WSB_WT    18432ull
#define WSB_PSC   51200ull       // [<=4800][128] f32 slot
#define WSB_PSQ   2508800ull
#define WSB_P2C   4966400ull
#define WSB_P2Q   5015552ull
#define WSB_SCL   5064704ull
#define WSB_SFT   5065216ull
#define WSB_Y     5065728ull     // [B*128][7500] bf16
#define WS_NEED2  127945728ull

static __device__ __forceinline__ unsigned short f2bf(float f) {
    unsigned int u = __float_as_uint(f);
    unsigned int r = (u + 0x7fffu + ((u >> 16) & 1u)) >> 16;
    return (unsigned short)r;
}
static __device__ __forceinline__ float bf2f(unsigned short u) {
    return __uint_as_float(((unsigned int)u) << 16);
}

// ---------------- standalone prep (fallback path only) ----------------
__global__ __launch_bounds__(256) void k_prep(const float* __restrict__ A,
                                              const float* __restrict__ W,
                                              const float* __restrict__ Wr,
                                              unsigned short* __restrict__ AF,
                                              unsigned short* __restrict__ Wt) {
    const int tid = threadIdx.x;
    if (blockIdx.x == 0) {
        __shared__ float Pall[8][625];
        for (int p = tid; p < 625; p += 256) Pall[0][p] = A[p];
        __syncthreads();
        for (int i = 1; i < 8; i++) {
            for (int p = tid; p < 625; p += 256) {
                int r = p / 25, c = p - r * 25;
                float s = 0.f;
                #pragma unroll 5
                for (int j = 0; j < 25; j++) s = fmaf(Pall[i-1][r*25 + j], A[j*25 + c], s);
                Pall[i][p] = s;
            }
            __syncthreads();
        }
        for (int idx = tid; idx < 18 * 64; idx += 256) {
            int fi = idx >> 6, l = idx & 63, qq = l >> 4, tt = l & 15;
            unsigned short v[8];
            #pragma unroll
            for (int e = 0; e < 8; e++) {
                int j = qq * 8 + e;
                float val = 0.f;
                if (fi < 16) {
                    int i = fi >> 1, k = (fi & 1) * 16 + tt;
                    if (j < 25 && k < 25) val = Pall[i][j * 25 + k];
                } else {
                    int k = (fi - 16) * 16 + tt;
                    if (j < 25 && k < 25 && j == k) val = 1.f;
                }
                v[e] = f2bf(val);
            }
            *(uint4*)(AF + idx * 8) = *(uint4*)v;
        }
    } else {
        const int oc = tid;
        const float* src = (oc < 128) ? (W + oc * 64) : (Wr + (oc - 128) * 64);
        unsigned short row[64];
        #pragma unroll
        for (int c = 0; c < 64; c++) row[c] = f2bf(src[c]);
        #pragma unroll
        for (int cc = 0; cc < 8; cc++)
            *(uint4*)(Wt + oc * 64 + cc * 8) = *(uint4*)(row + cc * 8);
    }
}

// ---------------- cooperative single-launch kernel (no register-Y) ----------------
__global__ __launch_bounds__(512, 4) void k_mega2(const float* __restrict__ x,
                                                  const float* __restrict__ A,
                                                  const float* __restrict__ W,
                                                  const float* __restrict__ Wr,
                                                  const float* __restrict__ gamma,
                                                  const float* __restrict__ beta,
                                                  unsigned short* __restrict__ AF,
                                                  unsigned short* __restrict__ Wt,
                                                  unsigned short* __restrict__ Yg,
                                                  float* __restrict__ psc,
                                                  float* __restrict__ psq,
                                                  float* __restrict__ out) {
    __shared__ __align__(16) unsigned short SM[8192 + HS_ROWS * HS_STRIDE];
    __shared__ float scl[128], sft[128];
    unsigned short* As = SM;
    unsigned short* Hs = SM + 8192;
    const int tid = threadIdx.x, wv = tid >> 6, ln = tid & 63;
    const int q = ln >> 4, t = ln & 15;
    const int s = wv >> 1, bh = wv & 1;

    // ---- inline prep (blocks 0,1) ----
    if (blockIdx.x == 0) {
        float* Pall = (float*)SM;          // 8*625 floats = 20 KB
        for (int p = tid; p < 625; p += 512) Pall[p] = A[p];
        __syncthreads();
        for (int i = 1; i < 8; i++) {
            for (int p = tid; p < 625; p += 512) {
                int r = p / 25, c = p - r * 25;
                float sx = 0.f;
                #pragma unroll 5
                for (int j = 0; j < 25; j++) sx = fmaf(Pall[(i-1)*625 + r*25 + j], A[j*25 + c], sx);
                Pall[i*625 + p] = sx;
            }
            __syncthreads();
        }
        for (int idx = tid; idx < 18 * 64; idx += 512) {
            int fi = idx >> 6, l = idx & 63, qq = l >> 4, tt = l & 15;
            unsigned short v[8];
            #pragma unroll
            for (int e = 0; e < 8; e++) {
                int j = qq * 8 + e;
                float val = 0.f;
                if (fi < 16) {
                    int i = fi >> 1, k = (fi & 1) * 16 + tt;
                    if (j < 25 && k < 25) val = Pall[i * 625 + j * 25 + k];
                } else {
                    int k = (fi - 16) * 16 + tt;
                    if (j < 25 && k < 25 && j == k) val = 1.f;
                }
                v[e] = f2bf(val);
            }
            *(uint4*)(AF + idx * 8) = *(uint4*)v;
        }
    } else if (blockIdx.x == 1 && tid < 256) {
        const int oc = tid;
        const float* src = (oc < 128) ? (W + oc * 64) : (Wr + (oc - 128) * 64);
        unsigned short row[64];
        #pragma unroll
        for (int c = 0; c < 64; c++) row[c] = f2bf(src[c]);
        #pragma unroll
        for (int cc = 0; cc < 8; cc++)
            *(uint4*)(Wt + oc * 64 + cc * 8) = *(uint4*)(row + cc * 8);
    }
    cg::this_grid().sync();

    const bf16x8* AFp = (const bf16x8*)AF;
    const bf16x8 id0 = AFp[16 * 64 + ln];
    const bf16x8 id1 = AFp[17 * 64 + ln];

    // zero pad rows once (stay zero across tiles)
    for (int w = tid; w < 896; w += 512) ((unsigned int*)As)[3200 + w] = 0u;
    for (int w = tid; w < 903; w += 512) ((unsigned int*)Hs)[12900 + w] = 0u;

    float sacc[4] = {0.f, 0.f, 0.f, 0.f}, qacc[4] = {0.f, 0.f, 0.f, 0.f};
    const int tile0 = blockIdx.x * TILES_PB;

    #pragma unroll 1
    for (int tl = 0; tl < TILES_PB; tl++) {
        const int tile = tile0 + tl;
        const int b = tile / 75, tg = tile - b * 75;
        __syncthreads();
        // stage x -> As
        for (int p = tid; p < 1600; p += 512) {
            int c = p / 25, e4 = p - c * 25;
            float4 f = *(const float4*)(x + ((size_t)(b * 64 + c)) * TV + tg * 100 + e4 * 4);
            float vv[4] = { f.x, f.y, f.z, f.w };
            #pragma unroll
            for (int u = 0; u < 4; u++) {
                int r = e4 * 4 + u;
                As[r * 64 + (((c >> 3) ^ (r & 7)) << 3) + (c & 7)] = f2bf(vv[u]);
            }
        }
        __syncthreads();
        // phase 1
        {
            const int rb = wv >> 2, oq = wv & 3;
            f32x4 acc[4][4] = {};
            #pragma unroll
            for (int ks = 0; ks < 2; ks++) {
                const unsigned short* wb = Wt + (oq * 64 + t) * 64 + q * 8 + ks * 32;
                bf16x8 bv[4], af[4];
                #pragma unroll
                for (int ni = 0; ni < 4; ni++) bv[ni] = *(const bf16x8*)(wb + ni * 1024);
                #pragma unroll
                for (int mi = 0; mi < 4; mi++) {
                    int row = rb * 64 + mi * 16 + t;
                    af[mi] = *(const bf16x8*)(As + row * 64 + (((ks * 4 + q) ^ (row & 7)) << 3));
                }
                #pragma unroll
                for (int mi = 0; mi < 4; mi++)
                    #pragma unroll
                    for (int ni = 0; ni < 4; ni++)
                        acc[mi][ni] = __builtin_amdgcn_mfma_f32_16x16x32_bf16(bv[ni], af[mi], acc[mi][ni], 0, 0, 0);
            }
            #pragma unroll
            for (int mi = 0; mi < 4; mi++) {
                int row = rb * 64 + mi * 16 + t;
                if (row < 100) {
                    #pragma unroll
                    for (int ni = 0; ni < 4; ni++) {
                        int co = oq * 64 + ni * 16 + q * 4;
                        unsigned int* dst = (unsigned int*)(Hs + row * HS_STRIDE + co);
                        dst[0] = (unsigned int)f2bf(acc[mi][ni][0]) | ((unsigned int)f2bf(acc[mi][ni][1]) << 16);
                        dst[1] = (unsigned int)f2bf(acc[mi][ni][2]) | ((unsigned int)f2bf(acc[mi][ni][3]) << 16);
                    }
                }
            }
        }
        __syncthreads();
        // phase 2: MFMA graph-apply + residual; stats to regs; D -> Hs
        {
            f32x4 acc2[4][2];
            #pragma unroll
            for (int ii = 0; ii < 4; ii++) { acc2[ii][0] = (f32x4){0,0,0,0}; acc2[ii][1] = (f32x4){0,0,0,0}; }
            const int rowq = (s * 25 + q * 8) * HS_STRIDE + t;
            #pragma unroll
            for (int ii = 0; ii < 4; ii++) {
                const int i = bh * 4 + ii;
                unsigned short hm[8], hr[8];
                #pragma unroll
                for (int e = 0; e < 8; e++) {
                    int a = rowq + e * HS_STRIDE + i * 16;
                    hm[e] = Hs[a];
                    hr[e] = Hs[a + 128];
                }
                bf16x8 bm = *(bf16x8*)hm;
                bf16x8 brs = *(bf16x8*)hr;
                bf16x8 a0 = AFp[(i * 2 + 0) * 64 + ln];
                bf16x8 a1 = AFp[(i * 2 + 1) * 64 + ln];
                acc2[ii][0] = __builtin_amdgcn_mfma_f32_16x16x32_bf16(id0, brs, acc2[ii][0], 0, 0, 0);
                acc2[ii][1] = __builtin_amdgcn_mfma_f32_16x16x32_bf16(id1, brs, acc2[ii][1], 0, 0, 0);
                acc2[ii][0] = __builtin_amdgcn_mfma_f32_16x16x32_bf16(a0, bm, acc2[ii][0], 0, 0, 0);
                acc2[ii][1] = __builtin_amdgcn_mfma_f32_16x16x32_bf16(a1, bm, acc2[ii][1], 0, 0, 0);
            }
            #pragma unroll
            for (int ii = 0; ii < 4; ii++) {
                float si = 0.f, qi = 0.f;
                #pragma unroll
                for (int mt = 0; mt < 2; mt++)
                    #pragma unroll
                    for (int r = 0; r < 4; r++) {
                        float v = acc2[ii][mt][r];
                        si += v; qi += v * v;
                    }
                sacc[ii] += si; qacc[ii] += qi;
            }
            #pragma unroll
            for (int ii = 0; ii < 4; ii++)
                #pragma unroll
                for (int mt = 0; mt < 2; mt++)
                    #pragma unroll
                    for (int r = 0; r < 4; r++) {
                        int k = mt * 16 + q * 4 + r;
                        if (k < 25)
                            Hs[(s * 25 + k) * HS_STRIDE + (bh * 4 + ii) * 16 + t] = f2bf(acc2[ii][mt][r]);
                    }
        }
        __syncthreads();
        // Y write (linear [b*128+o][7500])
        for (int idx = tid; idx < 3200; idx += 512) {
            int o = idx / 25, w = idx - o * 25;
            unsigned short vv[4];
            #pragma unroll
            for (int e = 0; e < 4; e++)
                vv[e] = Hs[(w * 4 + e) * HS_STRIDE + o];
            uint2 d;
            d.x = (unsigned int)vv[0] | ((unsigned int)vv[1] << 16);
            d.y = (unsigned int)vv[2] | ((unsigned int)vv[3] << 16);
            *(uint2*)(Yg + (size_t)(b * 128 + o) * TV + tg * 100 + w * 4) = d;
        }
    }

    // block BN partials -> global
    __syncthreads();
    float* ps = (float*)SM;
    float* qs = ps + 512;
    #pragma unroll
    for (int ii = 0; ii < 4; ii++) {
        float si = sacc[ii], qi = qacc[ii];
        si += __shfl_xor(si, 16); si += __shfl_xor(si, 32);
        qi += __shfl_xor(qi, 16); qi += __shfl_xor(qi, 32);
        if (ln < 16) {
            ps[s * 128 + (bh * 4 + ii) * 16 + t] = si;
            qs[s * 128 + (bh * 4 + ii) * 16 + t] = qi;
        }
    }
    __syncthreads();
    if (tid < 128) {
        psc[blockIdx.x * 128 + tid] = ps[tid] + ps[128 + tid] + ps[256 + tid] + ps[384 + tid];
        psq[blockIdx.x * 128 + tid] = qs[tid] + qs[128 + tid] + qs[256 + tid] + qs[384 + tid];
    }

    cg::this_grid().sync();

    // redundant per-block stats reduce (L2-resident 245KB x2) -> scl/sft
    {
        const int o = tid & 127, ph = tid >> 7;
        float S = 0.f, Q = 0.f;
        for (int i = ph; i < NBLK; i += 4) {
            S += psc[i * 128 + o];
            Q += psq[i * 128 + o];
        }
        ps[ph * 128 + o] = S;
        qs[ph * 128 + o] = Q;
        __syncthreads();
        if (tid < 128) {
            float St = ps[tid] + ps[128 + tid] + ps[256 + tid] + ps[384 + tid];
            float Qt = qs[tid] + qs[128 + tid] + qs[256 + tid] + qs[384 + tid];
            float inv = 1.f / (float)BTV;
            float mean = St * inv;
            float var = Qt * inv - mean * mean;
            float sc = gamma[tid] / sqrtf(var + 1e-5f);
            scl[tid] = sc;
            sft[tid] = beta[tid] - mean * sc;
        }
        __syncthreads();
    }

    // norm sweep: Y -> out, grid-stride, fully linear
    for (int it = 0; it < 32; it++) {
        size_t base = ((size_t)it * NBLK + blockIdx.x) * 512 + tid;
        size_t e0 = base * 8;
        if (e0 >= (size_t)NELEM) break;
        #pragma unroll
        for (int g = 0; g < 2; g++) {
            size_t e = e0 + (size_t)g * 4;
            int o = (int)((e / 7500) & 127);
            float sc = scl[o], sh = sft[o];
            uint2 v = *(const uint2*)(Yg + e);
            float4 d;
            d.x = fmaxf(fmaf(bf2f((unsigned short)(v.x & 0xffffu)), sc, sh), 0.f);
            d.y = fmaxf(fmaf(bf2f((unsigned short)(v.x >> 16)),     sc, sh), 0.f);
            d.z = fmaxf(fmaf(bf2f((unsigned short)(v.y & 0xffffu)), sc, sh), 0.f);
            d.w = fmaxf(fmaf(bf2f((unsigned short)(v.y >> 16)),     sc, sh), 0.f);
            *(float4*)(out + e) = d;
        }
    }
}

// =================== FALLBACK: exact round-10 path ===================
__global__ __launch_bounds__(512, 2) void k_fuse(const float* __restrict__ x,
                                                 const unsigned short* __restrict__ Wt,
                                                 const unsigned short* __restrict__ AF,
                                                 unsigned short* __restrict__ Yg,
                                                 float* __restrict__ psc,
                                                 float* __restrict__ psq) {
    __shared__ __align__(16) unsigned short SM[8192 + HS_ROWS * HS_STRIDE];
    unsigned short* As = SM;
    unsigned short* Hs = SM + 8192;
    const int tg = blockIdx.x, b = blockIdx.y;
    const int tid = threadIdx.x, wv = tid >> 6, ln = tid & 63;
    const int q = ln >> 4, t = ln & 15;

    for (int p = tid; p < 1600; p += 512) {
        int c = p / 25, e4 = p - c * 25;
        float4 f = *(const float4*)(x + ((size_t)(b * 64 + c)) * TV + tg * 100 + e4 * 4);
        float vv[4] = { f.x, f.y, f.z, f.w };
        #pragma unroll
        for (int u = 0; u < 4; u++) {
            int r = e4 * 4 + u;
            As[r * 64 + (((c >> 3) ^ (r & 7)) << 3) + (c & 7)] = f2bf(vv[u]);
        }
    }
    for (int w = tid; w < 896; w += 512) ((unsigned int*)As)[3200 + w] = 0u;
    for (int w = tid; w < 903; w += 512) ((unsigned int*)Hs)[12900 + w] = 0u;
    __syncthreads();
    {
        const int rb = wv >> 2, oq = wv & 3;
        f32x4 acc[4][4] = {};
        #pragma unroll
        for (int ks = 0; ks < 2; ks++) {
            const unsigned short* wb = Wt + (oq * 64 + t) * 64 + q * 8 + ks * 32;
            bf16x8 bv[4], af[4];
            #pragma unroll
            for (int ni = 0; ni < 4; ni++) bv[ni] = *(const bf16x8*)(wb + ni * 1024);
            #pragma unroll
            for (int mi = 0; mi < 4; mi++) {
                int row = rb * 64 + mi * 16 + t;
                af[mi] = *(const bf16x8*)(As + row * 64 + (((ks * 4 + q) ^ (row & 7)) << 3));
            }
            #pragma unroll
            for (int mi = 0; mi < 4; mi++)
                #pragma unroll
                for (int ni = 0; ni < 4; ni++)
                    acc[mi][ni] = __builtin_amdgcn_mfma_f32_16x16x32_bf16(bv[ni], af[mi], acc[mi][ni], 0, 0, 0);
        }
        #pragma unroll
        for (int mi = 0; mi < 4; mi++) {
            int row = rb * 64 + mi * 16 + t;
            if (row < 100) {
                #pragma unroll
                for (int ni = 0; ni < 4; ni++) {
                    int co = oq * 64 + ni * 16 + q * 4;
                    unsigned int* dst = (unsigned int*)(Hs + row * HS_STRIDE + co);
                    dst[0] = (unsigned int)f2bf(acc[mi][ni][0]) | ((unsigned int)f2bf(acc[mi][ni][1]) << 16);
                    dst[1] = (unsigned int)f2bf(acc[mi][ni][2]) | ((unsigned int)f2bf(acc[mi][ni][3]) << 16);
                }
            }
        }
    }
    __syncthreads();
    const int s = wv >> 1, bh = wv & 1;
    const bf16x8* AFp = (const bf16x8*)AF;
    const bf16x8 id0 = AFp[16 * 64 + ln];
    const bf16x8 id1 = AFp[17 * 64 + ln];
    f32x4 acc2[4][2];
    #pragma unroll
    for (int ii = 0; ii < 4; ii++) { acc2[ii][0] = (f32x4){0,0,0,0}; acc2[ii][1] = (f32x4){0,0,0,0}; }
    const int rowq = (s * 25 + q * 8) * HS_STRIDE + t;
    #pragma unroll
    for (int ii = 0; ii < 4; ii++) {
        const int i = bh * 4 + ii;
        unsigned short hm[8], hr[8];
        #pragma unroll
        for (int e = 0; e < 8; e++) {
            int a = rowq + e * HS_STRIDE + i * 16;
            hm[e] = Hs[a];
            hr[e] = Hs[a + 128];
        }
        bf16x8 bm = *(bf16x8*)hm;
        bf16x8 brs = *(bf16x8*)hr;
        bf16x8 a0 = AFp[(i * 2 + 0) * 64 + ln];
        bf16x8 a1 = AFp[(i * 2 + 1) * 64 + ln];
        acc2[ii][0] = __builtin_amdgcn_mfma_f32_16x16x32_bf16(id0, brs, acc2[ii][0], 0, 0, 0);
        acc2[ii][1] = __builtin_amdgcn_mfma_f32_16x16x32_bf16(id1, brs, acc2[ii][1], 0, 0, 0);
        acc2[ii][0] = __builtin_amdgcn_mfma_f32_16x16x32_bf16(a0, bm, acc2[ii][0], 0, 0, 0);
        acc2[ii][1] = __builtin_amdgcn_mfma_f32_16x16x32_bf16(a1, bm, acc2[ii][1], 0, 0, 0);
    }
    float* ps = (float*)SM;
    float* qs = ps + 512;
    #pragma unroll
    for (int ii = 0; ii < 4; ii++) {
        float si = 0.f, qi = 0.f;
        #pragma unroll
        for (int mt = 0; mt < 2; mt++)
            #pragma unroll
            for (int r = 0; r < 4; r++) {
                float v = acc2[ii][mt][r];
                si += v; qi += v * v;
            }
        si += __shfl_xor(si, 16); si += __shfl_xor(si, 32);
        qi += __shfl_xor(qi, 16); qi += __shfl_xor(qi, 32);
        if (ln < 16) {
            ps[s * 128 + (bh * 4 + ii) * 16 + t] = si;
            qs[s * 128 + (bh * 4 + ii) * 16 + t] = qi;
        }
    }
    #pragma unroll
    for (int ii = 0; ii < 4; ii++)
        #pragma unroll
        for (int mt = 0; mt < 2; mt++)
            #pragma unroll
            for (int r = 0; r < 4; r++) {
                int k = mt * 16 + q * 4 + r;
                if (k < 25)
                    Hs[(s * 25 + k) * HS_STRIDE + (bh * 4 + ii) * 16 + t] = f2bf(acc2[ii][mt][r]);
            }
    __syncthreads();
    if (tid < 128) {
        float S = ps[tid] + ps[128 + tid] + ps[256 + tid] + ps[384 + tid];
        float Q = qs[tid] + qs[128 + tid] + qs[256 + tid] + qs[384 + tid];
        int blk = b * 75 + tg;
        psc[(size_t)blk * 128 + tid] = S;
        psq[(size_t)blk * 128 + tid] = Q;
    }
    for (int idx = tid; idx < 3200; idx += 512) {
        int o = idx / 25, w = idx - o * 25;
        unsigned short vv[4];
        #pragma unroll
        for (int e = 0; e < 4; e++)
            vv[e] = Hs[(w * 4 + e) * HS_STRIDE + o];
        uint2 d;
        d.x = (unsigned int)vv[0] | ((unsigned int)vv[1] << 16);
        d.y = (unsigned int)vv[2] | ((unsigned int)vv[3] << 16);
        *(uint2*)(Yg + (size_t)(b * 128 + o) * TV + tg * 100 + w * 4) = d;
    }
}

__global__ __launch_bounds__(256) void k_red1(const float* __restrict__ psc,
                                              const float* __restrict__ psq,
                                              float* __restrict__ p2c,
                                              float* __restrict__ p2q) {
    const int r = blockIdx.x;
    const int tid = threadIdx.x;
    const int o = tid & 127;
    const float* src = (tid < 128) ? psc : psq;
    float* dst = (tid < 128) ? p2c : p2q;
    float S = 0.f;
    for (int ii = 0; ii < 50; ii++)
        S += src[(size_t)(r * 50 + ii) * 128 + o];
    dst[r * 128 + o] = S;
}

__global__ void k_fin(const float* __restrict__ p2c, const float* __restrict__ p2q,
                      const float* __restrict__ gamma, const float* __restrict__ beta,
                      float* __restrict__ scale, float* __restrict__ shift) {
    const int o = threadIdx.x;
    if (o >= 128) return;
    float S = 0.f, Q = 0.f;
    for (int r = 0; r < 96; r++) { S += p2c[r * 128 + o]; Q += p2q[r * 128 + o]; }
    float inv = 1.f / (float)BTV;
    float mean = S * inv;
    float var = Q * inv - mean * mean;
    float sc = gamma[o] / sqrtf(var + 1e-5f);
    scale[o] = sc;
    shift[o] = beta[o] - mean * sc;
}

__global__ __launch_bounds__(256) void k_norm2(const unsigned short* __restrict__ Y,
                                               const float* __restrict__ scale,
                                               const float* __restrict__ shift,
                                               float* __restrict__ out) {
    size_t e0 = ((size_t)blockIdx.x * 256 + threadIdx.x) * 8;
    #pragma unroll
    for (int g = 0; g < 2; g++) {
        size_t e = e0 + (size_t)g * 4;
        int o = (int)((e / 7500) & 127);
        float sc = scale[o], sh = shift[o];
        uint2 v = *(const uint2*)(Y + e);
        float4 d;
        d.x = fmaxf(fmaf(bf2f((unsigned short)(v.x & 0xffffu)), sc, sh), 0.f);
        d.y = fmaxf(fmaf(bf2f((unsigned short)(v.x >> 16)),     sc, sh), 0.f);
        d.z = fmaxf(fmaf(bf2f((unsigned short)(v.y & 0xffffu)), sc, sh), 0.f);
        d.w = fmaxf(fmaf(bf2f((unsigned short)(v.y >> 16)),     sc, sh), 0.f);
        *(float4*)(out + e) = d;
    }
}

extern "C" void kernel_launch(void* const* d_in, const int* in_sizes, int n_in,
                              void* d_out, int out_size, void* d_ws, size_t ws_size,
                              hipStream_t stream) {
    const float* x     = (const float*)d_in[0];
    const float* A     = (const float*)d_in[1];
    const float* W     = (const float*)d_in[2];
    const float* Wr    = (const float*)d_in[3];
    const float* gamma = (const float*)d_in[5];
    const float* beta  = (const float*)d_in[6];
    float* out = (float*)d_out;
    char* wsb  = (char*)d_ws;
    if (ws_size < (size_t)WS_NEED2) return;

    unsigned short* AF  = (unsigned short*)(wsb + WSB_AF);
    unsigned short* Wt  = (unsigned short*)(wsb + WSB_WT);
    float*          psc = (float*)(wsb + WSB_PSC);
    float*          psq = (float*)(wsb + WSB_PSQ);
    float*          p2c = (float*)(wsb + WSB_P2C);
    float*          p2q = (float*)(wsb + WSB_P2Q);
    float*          scl = (float*)(wsb + WSB_SCL);
    float*          sft = (float*)(wsb + WSB_SFT);
    unsigned short* Y   = (unsigned short*)(wsb + WSB_Y);

    void* args[] = { (void*)&x, (void*)&A, (void*)&W, (void*)&Wr, (void*)&gamma, (void*)&beta,
                     (void*)&AF, (void*)&Wt, (void*)&Y, (void*)&psc, (void*)&psq, (void*)&out };
    hipError_t err = hipLaunchCooperativeKernel((const void*)k_mega2, dim3(NBLK), dim3(512),
                                                args, 0, stream);
    if (err != hipSuccess) {
        k_prep<<<2, 256, 0, stream>>>(A, W, Wr, AF, Wt);
        k_fuse<<<dim3(75, 64), 512, 0, stream>>>(x, Wt, AF, Y, psc, psq);
        k_red1<<<96, 256, 0, stream>>>(psc, psq, p2c, p2q);
        k_fin<<<1, 128, 0, stream>>>(p2c, p2q, gamma, beta, scl, sft);
        k_norm2<<<30000, 256, 0, stream>>>(Y, scl, sft, out);
    }
}

// Round 13
// 267.721 us; speedup vs baseline: 1.8816x; 1.8787x over previous
//
#include <hip/hip_runtime.h>
#include <hip/hip_bf16.h>

// Problem constants
#define B_  64
#define C_  64
#define T_  300
#define V_  25
#define O_  128
#define TV  (T_*V_)     // 7500
#define BTV (B_*T_*V_)  // 480000
#define HS_STRIDE 258   // LDS H row stride (shorts): conflict-free gather (129 dw = 1 mod 32)
#define HS_ROWS 57      // 50 rows + 7 pad (gather j<=31 from slab 1, base 25 -> row 56)
#define NPF 9600        // 64 b x 150 tgroups (2 t-slabs each)

typedef __bf16 bf16x8 __attribute__((ext_vector_type(8)));
typedef float f32x4 __attribute__((ext_vector_type(4)));

// ---- ws layout (byte offsets); ws proven >= 198,421,024 ----
#define WSB_AF    0ull           // A-fragment table [18][64][8] bf16 = 18432
#define WSB_WT    18432ull       // Wt[256][64] bf16 = 32768 -> 51200
#define WSB_PSC   51200ull       // [9600][128] f32 = 4,915,200
#define WSB_PSQ   4966400ull     // -> 9,881,600
#define WSB_SCL   9881600ull     // 128 f32 (slot 512)
#define WSB_SFT   9882112ull
#define WSB_Y     9882624ull     // [B*128][7500] bf16 = 122,880,000
#define WS_NEED2  132762624ull

static __device__ __forceinline__ unsigned short f2bf(float f) {
    unsigned int u = __float_as_uint(f);
    unsigned int r = (u + 0x7fffu + ((u >> 16) & 1u)) >> 16;
    return (unsigned short)r;
}
static __device__ __forceinline__ float bf2f(unsigned short u) {
    return __uint_as_float(((unsigned int)u) << 16);
}

// ---------------- prep: block 0 = A-power MFMA fragment table; block 1 = Wt ----
__global__ __launch_bounds__(256) void k_prep(const float* __restrict__ A,
                                              const float* __restrict__ W,
                                              const float* __restrict__ Wr,
                                              unsigned short* __restrict__ AF,
                                              unsigned short* __restrict__ Wt) {
    const int tid = threadIdx.x;
    if (blockIdx.x == 0) {
        __shared__ float Pall[8][625];
        for (int p = tid; p < 625; p += 256) Pall[0][p] = A[p];
        __syncthreads();
        for (int i = 1; i < 8; i++) {
            for (int p = tid; p < 625; p += 256) {
                int r = p / 25, c = p - r * 25;
                float s = 0.f;
                #pragma unroll 5
                for (int j = 0; j < 25; j++) s = fmaf(Pall[i-1][r*25 + j], A[j*25 + c], s);
                Pall[i][p] = s;
            }
            __syncthreads();
        }
        // AF[fi][lane][e]: fi<16: A^{i+1}[j][k], j=(l>>4)*8+e, k=(fi&1)*16+(l&15); fi=16,17: identity
        for (int idx = tid; idx < 18 * 64; idx += 256) {
            int fi = idx >> 6, l = idx & 63, qq = l >> 4, tt = l & 15;
            unsigned short v[8];
            #pragma unroll
            for (int e = 0; e < 8; e++) {
                int j = qq * 8 + e;
                float val = 0.f;
                if (fi < 16) {
                    int i = fi >> 1, k = (fi & 1) * 16 + tt;
                    if (j < 25 && k < 25) val = Pall[i][j * 25 + k];
                } else {
                    int k = (fi - 16) * 16 + tt;
                    if (j < 25 && k < 25 && j == k) val = 1.f;
                }
                v[e] = f2bf(val);
            }
            *(uint4*)(AF + idx * 8) = *(uint4*)v;
        }
    } else {
        const int oc = tid;
        const float* src = (oc < 128) ? (W + oc * 64) : (Wr + (oc - 128) * 64);
        unsigned short row[64];
        #pragma unroll
        for (int c = 0; c < 64; c++) row[c] = f2bf(src[c]);
        #pragma unroll
        for (int cc = 0; cc < 8; cc++)
            *(uint4*)(Wt + oc * 64 + cc * 8) = *(uint4*)(row + cc * 8);
    }
}

// ---------------- fused: x->H (MFMA) -> graph-apply (MFMA) + residual + BN + Y ----
// block: 256 thr (4 waves), 2 slabs (50 rows). 4 blocks/CU (37.6 KB LDS), 16 waves/CU,
// 4 independent barrier domains per CU -> barrier stalls hidden by sibling blocks.
__global__ __launch_bounds__(256, 4) void k_fuse(const float* __restrict__ x,
                                                 const unsigned short* __restrict__ Wt,
                                                 const unsigned short* __restrict__ AF,
                                                 unsigned short* __restrict__ Yg,
                                                 float* __restrict__ psc,
                                                 float* __restrict__ psq) {
    __shared__ __align__(16) unsigned short SM[4096 + HS_ROWS * HS_STRIDE];  // As | Hs
    unsigned short* As = SM;                 // [64 rows][64 c] u16 (rows 50..63 zero)
    unsigned short* Hs = SM + 4096;          // [57 rows][258] u16
    const int tg = blockIdx.x, b = blockIdx.y;   // tg 0..149 (2 t-slabs = 50 tv rows)
    const int tid = threadIdx.x, wv = tid >> 6, ln = tid & 63;
    const int q = ln >> 4, t = ln & 15;

    // stage x -> As bf16 [row=tv_local(0..49)][c], chunk-XOR swizzled by row&7
    for (int p = tid; p < 1600; p += 256) {
        int c = p / 25, e = p - c * 25;      // e = float2 index (25 per c)
        float2 f = *(const float2*)(x + ((size_t)(b * 64 + c)) * TV + tg * 50 + e * 2);
        int r0 = e * 2;
        As[r0 * 64 + (((c >> 3) ^ (r0 & 7)) << 3) + (c & 7)]         = f2bf(f.x);
        As[(r0+1) * 64 + (((c >> 3) ^ ((r0+1) & 7)) << 3) + (c & 7)] = f2bf(f.y);
    }
    // zero As pad rows 50..63 (dwords 1600..2047)
    for (int w = tid; w < 448; w += 256) ((unsigned int*)As)[1600 + w] = 0u;
    // zero Hs pad rows 50..56 (903 dwords from dw 6450)
    for (int w = tid; w < 903; w += 256) ((unsigned int*)Hs)[6450 + w] = 0u;
    __syncthreads();

    // phase 1: H[64 rows][256 oc] = As . Wt^T ; wave = oc-quad (64 oc x 64 rows)
    {
        const int oq = wv;
        f32x4 acc[4][4] = {};
        #pragma unroll
        for (int ks = 0; ks < 2; ks++) {
            const unsigned short* wb = Wt + (oq * 64 + t) * 64 + q * 8 + ks * 32;
            bf16x8 bv[4], af[4];
            #pragma unroll
            for (int ni = 0; ni < 4; ni++) bv[ni] = *(const bf16x8*)(wb + ni * 1024);
            #pragma unroll
            for (int mi = 0; mi < 4; mi++) {
                int row = mi * 16 + t;
                af[mi] = *(const bf16x8*)(As + row * 64 + (((ks * 4 + q) ^ (row & 7)) << 3));
            }
            #pragma unroll
            for (int mi = 0; mi < 4; mi++)
                #pragma unroll
                for (int ni = 0; ni < 4; ni++)
                    acc[mi][ni] = __builtin_amdgcn_mfma_f32_16x16x32_bf16(bv[ni], af[mi], acc[mi][ni], 0, 0, 0);
        }
        // epilogue: H -> Hs[row][oc] (u32-pair writes), rows < 50
        #pragma unroll
        for (int mi = 0; mi < 4; mi++) {
            int row = mi * 16 + t;
            if (row < 50) {
                #pragma unroll
                for (int ni = 0; ni < 4; ni++) {
                    int co = oq * 64 + ni * 16 + q * 4;
                    unsigned int* dst = (unsigned int*)(Hs + row * HS_STRIDE + co);
                    dst[0] = (unsigned int)f2bf(acc[mi][ni][0]) | ((unsigned int)f2bf(acc[mi][ni][1]) << 16);
                    dst[1] = (unsigned int)f2bf(acc[mi][ni][2]) | ((unsigned int)f2bf(acc[mi][ni][3]) << 16);
                }
            }
        }
    }
    __syncthreads();

    // phase 2: wave = (slab s in 0..1, branch-half bh); i = bh*4+ii
    const int s = wv >> 1, bh = wv & 1;
    const bf16x8* AFp = (const bf16x8*)AF;
    const bf16x8 id0 = AFp[16 * 64 + ln];
    const bf16x8 id1 = AFp[17 * 64 + ln];
    f32x4 acc2[4][2];
    #pragma unroll
    for (int ii = 0; ii < 4; ii++) { acc2[ii][0] = (f32x4){0,0,0,0}; acc2[ii][1] = (f32x4){0,0,0,0}; }
    const int rowq = (s * 25 + q * 8) * HS_STRIDE + t;
    #pragma unroll
    for (int ii = 0; ii < 4; ii++) {
        const int i = bh * 4 + ii;
        unsigned short hm[8], hr[8];
        #pragma unroll
        for (int e = 0; e < 8; e++) {
            int a = rowq + e * HS_STRIDE + i * 16;
            hm[e] = Hs[a];
            hr[e] = Hs[a + 128];
        }
        bf16x8 bm = *(bf16x8*)hm;
        bf16x8 brs = *(bf16x8*)hr;
        bf16x8 a0 = AFp[(i * 2 + 0) * 64 + ln];
        bf16x8 a1 = AFp[(i * 2 + 1) * 64 + ln];
        acc2[ii][0] = __builtin_amdgcn_mfma_f32_16x16x32_bf16(id0, brs, acc2[ii][0], 0, 0, 0);
        acc2[ii][1] = __builtin_amdgcn_mfma_f32_16x16x32_bf16(id1, brs, acc2[ii][1], 0, 0, 0);
        acc2[ii][0] = __builtin_amdgcn_mfma_f32_16x16x32_bf16(a0, bm, acc2[ii][0], 0, 0, 0);
        acc2[ii][1] = __builtin_amdgcn_mfma_f32_16x16x32_bf16(a1, bm, acc2[ii][1], 0, 0, 0);
    }
    // per-o BN partials (k>=25 slots exact zeros); waves write disjoint (s, o-half)
    float* ps = (float*)SM;            // As region dead (2048 floats available)
    float* qs = ps + 256;
    #pragma unroll
    for (int ii = 0; ii < 4; ii++) {
        float si = 0.f, qi = 0.f;
        #pragma unroll
        for (int mt = 0; mt < 2; mt++)
            #pragma unroll
            for (int r = 0; r < 4; r++) {
                float v = acc2[ii][mt][r];
                si += v; qi += v * v;
            }
        si += __shfl_xor(si, 16); si += __shfl_xor(si, 32);
        qi += __shfl_xor(qi, 16); qi += __shfl_xor(qi, 32);
        if (ln < 16) {
            ps[s * 128 + (bh * 4 + ii) * 16 + t] = si;
            qs[s * 128 + (bh * 4 + ii) * 16 + t] = qi;
        }
    }
    // D -> own-slab Hs rows (own column half; read set of other waves disjoint)
    #pragma unroll
    for (int ii = 0; ii < 4; ii++)
        #pragma unroll
        for (int mt = 0; mt < 2; mt++)
            #pragma unroll
            for (int r = 0; r < 4; r++) {
                int k = mt * 16 + q * 4 + r;
                if (k < 25)
                    Hs[(s * 25 + k) * HS_STRIDE + (bh * 4 + ii) * 16 + t] = f2bf(acc2[ii][mt][r]);
            }
    __syncthreads();
    if (tid < 128) {
        float S = ps[tid] + ps[128 + tid];
        float Q = qs[tid] + qs[128 + tid];
        int blk = b * 150 + tg;
        psc[(size_t)blk * 128 + tid] = S;
        psq[(size_t)blk * 128 + tid] = Q;
    }
    // Y write, linear [b*128+o][7500]: per o a 100B run, u32 stores
    for (int idx = tid; idx < 3200; idx += 256) {
        int o = idx / 25, w = idx - o * 25;          // w = u32 chunk (2 shorts)
        unsigned int d = (unsigned int)Hs[(w * 2) * HS_STRIDE + o]
                       | ((unsigned int)Hs[(w * 2 + 1) * HS_STRIDE + o] << 16);
        *(unsigned int*)(Yg + (size_t)(b * 128 + o) * TV + tg * 50 + w * 2) = d;
    }
}

// ---------------- merged stats reduce + BN finalize (128 blocks, one per o) ----
__global__ __launch_bounds__(256) void k_fin2(const float* __restrict__ psc,
                                              const float* __restrict__ psq,
                                              const float* __restrict__ gamma,
                                              const float* __restrict__ beta,
                                              float* __restrict__ scale,
                                              float* __restrict__ shift) {
    const int o = blockIdx.x, tid = threadIdx.x;
    float S = 0.f, Q = 0.f;
    for (int i = tid; i < NPF; i += 256) {
        S += psc[(size_t)i * 128 + o];
        Q += psq[(size_t)i * 128 + o];
    }
    #pragma unroll
    for (int m = 1; m < 64; m <<= 1) { S += __shfl_xor(S, m); Q += __shfl_xor(Q, m); }
    __shared__ float ls[4], lq[4];
    int w = tid >> 6;
    if ((tid & 63) == 0) { ls[w] = S; lq[w] = Q; }
    __syncthreads();
    if (tid == 0) {
        float St = ls[0] + ls[1] + ls[2] + ls[3];
        float Qt = lq[0] + lq[1] + lq[2] + lq[3];
        float inv = 1.f / (float)BTV;
        float mean = St * inv;
        float var = Qt * inv - mean * mean;
        float sc = gamma[o] / sqrtf(var + 1e-5f);
        scale[o] = sc;
        shift[o] = beta[o] - mean * sc;
    }
}

// ---------------- norm: Y[bo][7500] bf16 -> out f32, fully linear both sides ----
__global__ __launch_bounds__(256) void k_norm2(const unsigned short* __restrict__ Y,
                                               const float* __restrict__ scale,
                                               const float* __restrict__ shift,
                                               float* __restrict__ out) {
    size_t e0 = ((size_t)blockIdx.x * 256 + threadIdx.x) * 8;
    #pragma unroll
    for (int g = 0; g < 2; g++) {
        size_t e = e0 + (size_t)g * 4;
        int o = (int)((e / 7500) & 127);
        float sc = scale[o], sh = shift[o];
        uint2 v = *(const uint2*)(Y + e);
        float4 d;
        d.x = fmaxf(fmaf(bf2f((unsigned short)(v.x & 0xffffu)), sc, sh), 0.f);
        d.y = fmaxf(fmaf(bf2f((unsigned short)(v.x >> 16)),     sc, sh), 0.f);
        d.z = fmaxf(fmaf(bf2f((unsigned short)(v.y & 0xffffu)), sc, sh), 0.f);
        d.w = fmaxf(fmaf(bf2f((unsigned short)(v.y >> 16)),     sc, sh), 0.f);
        *(float4*)(out + e) = d;
    }
}

extern "C" void kernel_launch(void* const* d_in, const int* in_sizes, int n_in,
                              void* d_out, int out_size, void* d_ws, size_t ws_size,
                              hipStream_t stream) {
    const float* x     = (const float*)d_in[0];
    const float* A     = (const float*)d_in[1];
    const float* W     = (const float*)d_in[2];
    const float* Wr    = (const float*)d_in[3];
    const float* gamma = (const float*)d_in[5];
    const float* beta  = (const float*)d_in[6];
    float* out = (float*)d_out;
    char* wsb  = (char*)d_ws;
    if (ws_size < (size_t)WS_NEED2) return;

    unsigned short* AF  = (unsigned short*)(wsb + WSB_AF);
    unsigned short* Wt  = (unsigned short*)(wsb + WSB_WT);
    float*          psc = (float*)(wsb + WSB_PSC);
    float*          psq = (float*)(wsb + WSB_PSQ);
    float*          scl = (float*)(wsb + WSB_SCL);
    float*          sft = (float*)(wsb + WSB_SFT);
    unsigned short* Y   = (unsigned short*)(wsb + WSB_Y);

    k_prep<<<2, 256, 0, stream>>>(A, W, Wr, AF, Wt);
    k_fuse<<<dim3(150, 64), 256, 0, stream>>>(x, Wt, AF, Y, psc, psq);
    k_fin2<<<128, 256, 0, stream>>>(psc, psq, gamma, beta, scl, sft);
    k_norm2<<<30000, 256, 0, stream>>>(Y, scl, sft, out);
}

// Round 14
// 237.032 us; speedup vs baseline: 2.1252x; 1.1295x over previous
//
#include <hip/hip_runtime.h>
#include <hip/hip_bf16.h>

// Problem constants
#define B_  64
#define C_  64
#define T_  300
#define V_  25
#define O_  128
#define TV  (T_*V_)     // 7500
#define BTV (B_*T_*V_)  // 480000
#define NPF 4800        // 64 b x 75 tgroups (4 slabs each)

typedef __bf16 bf16x8 __attribute__((ext_vector_type(8)));
typedef float f32x4 __attribute__((ext_vector_type(4)));

// ---- ws layout (byte offsets); ws proven >= 198,421,024 ----
#define WSB_AF    0ull           // A-fragment table [18][64][8] bf16 = 18432
#define WSB_WT    18432ull       // Wt[256][64] bf16 = 32768 -> 51200
#define WSB_PSC   51200ull       // [4800][128] f32
#define WSB_PSQ   4966400ull
#define WSB_SCL   9881600ull
#define WSB_SFT   9882112ull
#define WSB_Y     9882624ull     // [B*128][7500] bf16 = 122,880,000
#define WS_NEED2  132762624ull

static __device__ __forceinline__ unsigned short f2bf(float f) {
    unsigned int u = __float_as_uint(f);
    unsigned int r = (u + 0x7fffu + ((u >> 16) & 1u)) >> 16;
    return (unsigned short)r;
}
static __device__ __forceinline__ float bf2f(unsigned short u) {
    return __uint_as_float(((unsigned int)u) << 16);
}

// ---------------- prep: block 0 = A-power MFMA fragment table; block 1 = Wt ----
__global__ __launch_bounds__(256) void k_prep(const float* __restrict__ A,
                                              const float* __restrict__ W,
                                              const float* __restrict__ Wr,
                                              unsigned short* __restrict__ AF,
                                              unsigned short* __restrict__ Wt) {
    const int tid = threadIdx.x;
    if (blockIdx.x == 0) {
        __shared__ float Pall[8][625];
        for (int p = tid; p < 625; p += 256) Pall[0][p] = A[p];
        __syncthreads();
        for (int i = 1; i < 8; i++) {
            for (int p = tid; p < 625; p += 256) {
                int r = p / 25, c = p - r * 25;
                float s = 0.f;
                #pragma unroll 5
                for (int j = 0; j < 25; j++) s = fmaf(Pall[i-1][r*25 + j], A[j*25 + c], s);
                Pall[i][p] = s;
            }
            __syncthreads();
        }
        // AF[fi][lane][e]: fi<16: A^{i+1}[j][k], j=(l>>4)*8+e, k=(fi&1)*16+(l&15); fi=16,17: identity
        for (int idx = tid; idx < 18 * 64; idx += 256) {
            int fi = idx >> 6, l = idx & 63, qq = l >> 4, tt = l & 15;
            unsigned short v[8];
            #pragma unroll
            for (int e = 0; e < 8; e++) {
                int j = qq * 8 + e;
                float val = 0.f;
                if (fi < 16) {
                    int i = fi >> 1, k = (fi & 1) * 16 + tt;
                    if (j < 25 && k < 25) val = Pall[i][j * 25 + k];
                } else {
                    int k = (fi - 16) * 16 + tt;
                    if (j < 25 && k < 25 && j == k) val = 1.f;
                }
                v[e] = f2bf(val);
            }
            *(uint4*)(AF + idx * 8) = *(uint4*)v;
        }
    } else {
        const int oc = tid;
        const float* src = (oc < 128) ? (W + oc * 64) : (Wr + (oc - 128) * 64);
        unsigned short row[64];
        #pragma unroll
        for (int c = 0; c < 64; c++) row[c] = f2bf(src[c]);
        #pragma unroll
        for (int cc = 0; cc < 8; cc++)
            *(uint4*)(Wt + oc * 64 + cc * 8) = *(uint4*)(row + cc * 8);
    }
}

// ---------------- fused: x->H (MFMA) -> graph-apply (MFMA) + residual + BN + Y ----
// 512 thr (8 waves), 4 slabs (100 rows), 2 blocks/CU (80 KB LDS).
// H stored TRANSPOSED: Hs2[oc][s*32+j] bf16, 8-short granule swizzle
//   g = (s*4 + (j>>3)) ^ (oc & 15); phase-2 B-fragment = one aligned ds_read_b128.
__global__ __launch_bounds__(512, 2) void k_fuse(const float* __restrict__ x,
                                                 const unsigned short* __restrict__ Wt,
                                                 const unsigned short* __restrict__ AF,
                                                 unsigned short* __restrict__ Yg,
                                                 float* __restrict__ psc,
                                                 float* __restrict__ psq) {
    __shared__ __align__(16) unsigned short SM[8192 + 256 * 128];  // As 16KB | Hs2 64KB
    unsigned short* As  = SM;            // [128 rows][64 c] (rows 100..127 zero)
    unsigned short* Hs2 = SM + 8192;     // [256 oc][128] transposed H
    const int tg = blockIdx.x, b = blockIdx.y;    // tg 0..74 (4 slabs = 100 tv rows)
    const int tid = threadIdx.x, wv = tid >> 6, ln = tid & 63;
    const int q = ln >> 4, t = ln & 15;

    // stage x -> As bf16 [row=tv_local(0..99)][c], chunk-XOR swizzled by row&7
    for (int p = tid; p < 1600; p += 512) {
        int c = p / 25, e4 = p - c * 25;
        float4 f = *(const float4*)(x + ((size_t)(b * 64 + c)) * TV + tg * 100 + e4 * 4);
        float vv[4] = { f.x, f.y, f.z, f.w };
        #pragma unroll
        for (int u = 0; u < 4; u++) {
            int r = e4 * 4 + u;
            As[r * 64 + (((c >> 3) ^ (r & 7)) << 3) + (c & 7)] = f2bf(vv[u]);
        }
    }
    // zero As pad rows 100..127
    for (int w = tid; w < 896; w += 512) ((unsigned int*)As)[3200 + w] = 0u;
    // zero Hs2 pad granules (lg = s*4+3 holds j=24..31; j=24 overwritten by phase 1)
    for (int gi = tid; gi < 1024; gi += 512) {
        int oc = gi >> 2, s = gi & 3;
        int g = (s * 4 + 3) ^ (oc & 15);
        *(uint4*)(Hs2 + oc * 128 + g * 8) = (uint4){0u, 0u, 0u, 0u};
    }
    __syncthreads();

    // phase 1: H[128 rows][256 oc] = As . Wt^T ; wave = (rowblock rb, oc-quad oq)
    {
        const int rb = wv >> 2, oq = wv & 3;
        f32x4 acc[4][4] = {};
        #pragma unroll
        for (int ks = 0; ks < 2; ks++) {
            const unsigned short* wb = Wt + (oq * 64 + t) * 64 + q * 8 + ks * 32;
            bf16x8 bv[4], af[4];
            #pragma unroll
            for (int ni = 0; ni < 4; ni++) bv[ni] = *(const bf16x8*)(wb + ni * 1024);
            #pragma unroll
            for (int mi = 0; mi < 4; mi++) {
                int row = rb * 64 + mi * 16 + t;
                af[mi] = *(const bf16x8*)(As + row * 64 + (((ks * 4 + q) ^ (row & 7)) << 3));
            }
            #pragma unroll
            for (int mi = 0; mi < 4; mi++)
                #pragma unroll
                for (int ni = 0; ni < 4; ni++)
                    acc[mi][ni] = __builtin_amdgcn_mfma_f32_16x16x32_bf16(bv[ni], af[mi], acc[mi][ni], 0, 0, 0);
        }
        // epilogue: H -> Hs2[co][s*32+j] (b16 writes), rows < 100
        #pragma unroll
        for (int mi = 0; mi < 4; mi++) {
            int row = rb * 64 + mi * 16 + t;
            if (row < 100) {
                int ss = row / 25, jj = row - ss * 25;
                int lg = ss * 4 + (jj >> 3), off = jj & 7;
                #pragma unroll
                for (int ni = 0; ni < 4; ni++) {
                    int co = oq * 64 + ni * 16 + q * 4;
                    #pragma unroll
                    for (int r = 0; r < 4; r++)
                        Hs2[(co + r) * 128 + ((lg ^ (q * 4 + r)) << 3) + off] = f2bf(acc[mi][ni][r]);
                }
            }
        }
    }
    __syncthreads();

    // phase 2: wave = (slab s, branch-half bh); i = bh*4+ii
    const int s = wv >> 1, bh = wv & 1;
    const bf16x8* AFp = (const bf16x8*)AF;
    const bf16x8 id0 = AFp[16 * 64 + ln];
    const bf16x8 id1 = AFp[17 * 64 + ln];
    f32x4 acc2[4][2];
    #pragma unroll
    for (int ii = 0; ii < 4; ii++) { acc2[ii][0] = (f32x4){0,0,0,0}; acc2[ii][1] = (f32x4){0,0,0,0}; }
    const int g2 = ((s * 4 + q) ^ t) * 8;   // granule byte-offset base (shorts), lane-constant
    #pragma unroll
    for (int ii = 0; ii < 4; ii++) {
        const int i = bh * 4 + ii;
        bf16x8 bm  = *(const bf16x8*)(Hs2 + (i * 16 + t) * 128 + g2);         // H[q*8+e][i*16+t]
        bf16x8 brs = *(const bf16x8*)(Hs2 + (128 + i * 16 + t) * 128 + g2);   // residual half
        bf16x8 a0 = AFp[(i * 2 + 0) * 64 + ln];
        bf16x8 a1 = AFp[(i * 2 + 1) * 64 + ln];
        acc2[ii][0] = __builtin_amdgcn_mfma_f32_16x16x32_bf16(id0, brs, acc2[ii][0], 0, 0, 0);
        acc2[ii][1] = __builtin_amdgcn_mfma_f32_16x16x32_bf16(id1, brs, acc2[ii][1], 0, 0, 0);
        acc2[ii][0] = __builtin_amdgcn_mfma_f32_16x16x32_bf16(a0, bm, acc2[ii][0], 0, 0, 0);
        acc2[ii][1] = __builtin_amdgcn_mfma_f32_16x16x32_bf16(a1, bm, acc2[ii][1], 0, 0, 0);
    }
    // per-o BN partials (k>=25 slots exact zeros)
    float* ps = (float*)SM;            // As region dead
    float* qs = ps + 512;
    #pragma unroll
    for (int ii = 0; ii < 4; ii++) {
        float si = 0.f, qi = 0.f;
        #pragma unroll
        for (int mt = 0; mt < 2; mt++)
            #pragma unroll
            for (int r = 0; r < 4; r++) {
                float v = acc2[ii][mt][r];
                si += v; qi += v * v;
            }
        si += __shfl_xor(si, 16); si += __shfl_xor(si, 32);
        qi += __shfl_xor(qi, 16); qi += __shfl_xor(qi, 32);
        if (ln < 16) {
            ps[s * 128 + (bh * 4 + ii) * 16 + t] = si;
            qs[s * 128 + (bh * 4 + ii) * 16 + t] = qi;
        }
    }
    // D -> Hs2[o][s*32+k] (own-slab columns, own o-half: disjoint from other waves' reads)
    #pragma unroll
    for (int ii = 0; ii < 4; ii++) {
        const int o = (bh * 4 + ii) * 16 + t;
        #pragma unroll
        for (int mt = 0; mt < 2; mt++)
            #pragma unroll
            for (int r = 0; r < 4; r++) {
                int k = mt * 16 + q * 4 + r;
                if (k < 25)
                    Hs2[o * 128 + (((s * 4 + (k >> 3)) ^ t) << 3) + (k & 7)] = f2bf(acc2[ii][mt][r]);
            }
    }
    __syncthreads();
    if (tid < 128) {
        float S = ps[tid] + ps[128 + tid] + ps[256 + tid] + ps[384 + tid];
        float Q = qs[tid] + qs[128 + tid] + qs[256 + tid] + qs[384 + tid];
        int blk = b * 75 + tg;
        psc[(size_t)blk * 128 + tid] = S;
        psq[(size_t)blk * 128 + tid] = Q;
    }
    // Y write, linear [b*128+o][7500]: per-o 200B runs, uint2 stores
    for (int idx = tid; idx < 3200; idx += 512) {
        int o = idx / 25, w = idx - o * 25;
        unsigned short vv[4];
        #pragma unroll
        for (int e = 0; e < 4; e++) {
            int tk = w * 4 + e;
            int ss = tk / 25, kk = tk - ss * 25;
            vv[e] = Hs2[o * 128 + (((ss * 4 + (kk >> 3)) ^ (o & 15)) << 3) + (kk & 7)];
        }
        uint2 d;
        d.x = (unsigned int)vv[0] | ((unsigned int)vv[1] << 16);
        d.y = (unsigned int)vv[2] | ((unsigned int)vv[3] << 16);
        *(uint2*)(Yg + (size_t)(b * 128 + o) * TV + tg * 100 + w * 4) = d;
    }
}

// ---------------- merged stats reduce + BN finalize (128 blocks, one per o) ----
__global__ __launch_bounds__(256) void k_fin2(const float* __restrict__ psc,
                                              const float* __restrict__ psq,
                                              const float* __restrict__ gamma,
                                              const float* __restrict__ beta,
                                              float* __restrict__ scale,
                                              float* __restrict__ shift) {
    const int o = blockIdx.x, tid = threadIdx.x;
    float S = 0.f, Q = 0.f;
    for (int i = tid; i < NPF; i += 256) {
        S += psc[(size_t)i * 128 + o];
        Q += psq[(size_t)i * 128 + o];
    }
    #pragma unroll
    for (int m = 1; m < 64; m <<= 1) { S += __shfl_xor(S, m); Q += __shfl_xor(Q, m); }
    __shared__ float ls[4], lq[4];
    int w = tid >> 6;
    if ((tid & 63) == 0) { ls[w] = S; lq[w] = Q; }
    __syncthreads();
    if (tid == 0) {
        float St = ls[0] + ls[1] + ls[2] + ls[3];
        float Qt = lq[0] + lq[1] + lq[2] + lq[3];
        float inv = 1.f / (float)BTV;
        float mean = St * inv;
        float var = Qt * inv - mean * mean;
        float sc = gamma[o] / sqrtf(var + 1e-5f);
        scale[o] = sc;
        shift[o] = beta[o] - mean * sc;
    }
}

// ---------------- norm: Y[bo][7500] bf16 -> out f32, fully linear both sides ----
__global__ __launch_bounds__(256) void k_norm2(const unsigned short* __restrict__ Y,
                                               const float* __restrict__ scale,
                                               const float* __restrict__ shift,
                                               float* __restrict__ out) {
    size_t e0 = ((size_t)blockIdx.x * 256 + threadIdx.x) * 8;
    #pragma unroll
    for (int g = 0; g < 2; g++) {
        size_t e = e0 + (size_t)g * 4;
        int o = (int)((e / 7500) & 127);
        float sc = scale[o], sh = shift[o];
        uint2 v = *(const uint2*)(Y + e);
        float4 d;
        d.x = fmaxf(fmaf(bf2f((unsigned short)(v.x & 0xffffu)), sc, sh), 0.f);
        d.y = fmaxf(fmaf(bf2f((unsigned short)(v.x >> 16)),     sc, sh), 0.f);
        d.z = fmaxf(fmaf(bf2f((unsigned short)(v.y & 0xffffu)), sc, sh), 0.f);
        d.w = fmaxf(fmaf(bf2f((unsigned short)(v.y >> 16)),     sc, sh), 0.f);
        *(float4*)(out + e) = d;
    }
}

extern "C" void kernel_launch(void* const* d_in, const int* in_sizes, int n_in,
                              void* d_out, int out_size, void* d_ws, size_t ws_size,
                              hipStream_t stream) {
    const float* x     = (const float*)d_in[0];
    const float* A     = (const float*)d_in[1];
    const float* W     = (const float*)d_in[2];
    const float* Wr    = (const float*)d_in[3];
    const float* gamma = (const float*)d_in[5];
    const float* beta  = (const float*)d_in[6];
    float* out = (float*)d_out;
    char* wsb  = (char*)d_ws;
    if (ws_size < (size_t)WS_NEED2) return;

    unsigned short* AF  = (unsigned short*)(wsb + WSB_AF);
    unsigned short* Wt  = (unsigned short*)(wsb + WSB_WT);
    float*          psc = (float*)(wsb + WSB_PSC);
    float*          psq = (float*)(wsb + WSB_PSQ);
    float*          scl = (float*)(wsb + WSB_SCL);
    float*          sft = (float*)(wsb + WSB_SFT);
    unsigned short* Y   = (unsigned short*)(wsb + WSB_Y);

    k_prep<<<2, 256, 0, stream>>>(A, W, Wr, AF, Wt);
    k_fuse<<<dim3(75, 64), 512, 0, stream>>>(x, Wt, AF, Y, psc, psq);
    k_fin2<<<128, 256, 0, stream>>>(psc, psq, gamma, beta, scl, sft);
    k_norm2<<<30000, 256, 0, stream>>>(Y, scl, sft, out);
}

// Round 15
// 231.704 us; speedup vs baseline: 2.1740x; 1.0230x over previous
//
#include <hip/hip_runtime.h>
#include <hip/hip_bf16.h>

// Problem constants
#define B_  64
#define C_  64
#define T_  300
#define V_  25
#define O_  128
#define TV  (T_*V_)     // 7500
#define BTV (B_*T_*V_)  // 480000
#define HS_STRIDE 258   // LDS H row stride (shorts): conflict-free gather
#define HS_ROWS 107
#define NPF 4800        // 64 b x 75 tgroups (4 slabs each)

typedef __bf16 bf16x8 __attribute__((ext_vector_type(8)));
typedef float f32x4 __attribute__((ext_vector_type(4)));

// ---- ws layout (byte offsets) ----
#define WSB_AF    0ull           // A-fragment table [18][64][8] bf16 = 18432
#define WSB_WT    18432ull       // Wt[256][64] bf16 = 32768 -> 51200
#define WSB_PSC   51200ull       // [4800][128] f32
#define WSB_PSQ   2508800ull
#define WSB_SCL   5064704ull
#define WSB_SFT   5065216ull
#define WSB_Y     5065728ull     // [B*128][7500] bf16 = 122,880,000
#define WS_NEED2  127945728ull

static __device__ __forceinline__ unsigned short f2bf(float f) {
    unsigned int u = __float_as_uint(f);
    unsigned int r = (u + 0x7fffu + ((u >> 16) & 1u)) >> 16;
    return (unsigned short)r;
}
static __device__ __forceinline__ float bf2f(unsigned short u) {
    return __uint_as_float(((unsigned int)u) << 16);
}

// ---------------- prep: block 0 = A-power MFMA fragment table; block 1 = Wt ----
__global__ __launch_bounds__(256) void k_prep(const float* __restrict__ A,
                                              const float* __restrict__ W,
                                              const float* __restrict__ Wr,
                                              unsigned short* __restrict__ AF,
                                              unsigned short* __restrict__ Wt) {
    const int tid = threadIdx.x;
    if (blockIdx.x == 0) {
        __shared__ float Pall[8][625];
        for (int p = tid; p < 625; p += 256) Pall[0][p] = A[p];
        __syncthreads();
        for (int i = 1; i < 8; i++) {
            for (int p = tid; p < 625; p += 256) {
                int r = p / 25, c = p - r * 25;
                float s = 0.f;
                #pragma unroll 5
                for (int j = 0; j < 25; j++) s = fmaf(Pall[i-1][r*25 + j], A[j*25 + c], s);
                Pall[i][p] = s;
            }
            __syncthreads();
        }
        // AF[fi][lane][e]: fi<16: A^{i+1}[j][k], j=(l>>4)*8+e, k=(fi&1)*16+(l&15); fi=16,17: identity
        for (int idx = tid; idx < 18 * 64; idx += 256) {
            int fi = idx >> 6, l = idx & 63, qq = l >> 4, tt = l & 15;
            unsigned short v[8];
            #pragma unroll
            for (int e = 0; e < 8; e++) {
                int j = qq * 8 + e;
                float val = 0.f;
                if (fi < 16) {
                    int i = fi >> 1, k = (fi & 1) * 16 + tt;
                    if (j < 25 && k < 25) val = Pall[i][j * 25 + k];
                } else {
                    int k = (fi - 16) * 16 + tt;
                    if (j < 25 && k < 25 && j == k) val = 1.f;
                }
                v[e] = f2bf(val);
            }
            *(uint4*)(AF + idx * 8) = *(uint4*)v;
        }
    } else {
        const int oc = tid;
        const float* src = (oc < 128) ? (W + oc * 64) : (Wr + (oc - 128) * 64);
        unsigned short row[64];
        #pragma unroll
        for (int c = 0; c < 64; c++) row[c] = f2bf(src[c]);
        #pragma unroll
        for (int cc = 0; cc < 8; cc++)
            *(uint4*)(Wt + oc * 64 + cc * 8) = *(uint4*)(row + cc * 8);
    }
}

// ---------------- fused: x->H (MFMA) -> graph-apply (MFMA) + residual + BN + Y ----
// block: 512 thr (8 waves), 4 slabs (100 rows). 2 blocks/CU (71.6 KB LDS), 16 waves/CU.
__global__ __launch_bounds__(512, 2) void k_fuse(const float* __restrict__ x,
                                                 const unsigned short* __restrict__ Wt,
                                                 const unsigned short* __restrict__ AF,
                                                 unsigned short* __restrict__ Yg,
                                                 float* __restrict__ psc,
                                                 float* __restrict__ psq) {
    __shared__ __align__(16) unsigned short SM[8192 + HS_ROWS * HS_STRIDE];  // As | Hs
    unsigned short* As = SM;
    unsigned short* Hs = SM + 8192;
    const int tg = blockIdx.x, b = blockIdx.y;          // tg 0..74 (4 t-slabs)
    const int tid = threadIdx.x, wv = tid >> 6, ln = tid & 63;
    const int q = ln >> 4, t = ln & 15;

    // stage x -> As bf16 [row=tv_local(0..99)][c], chunk-XOR swizzled by row&7
    for (int p = tid; p < 1600; p += 512) {
        int c = p / 25, e4 = p - c * 25;
        float4 f = *(const float4*)(x + ((size_t)(b * 64 + c)) * TV + tg * 100 + e4 * 4);
        float vv[4] = { f.x, f.y, f.z, f.w };
        #pragma unroll
        for (int u = 0; u < 4; u++) {
            int r = e4 * 4 + u;
            As[r * 64 + (((c >> 3) ^ (r & 7)) << 3) + (c & 7)] = f2bf(vv[u]);
        }
    }
    // zero As pad rows 100..127 (dwords 3200..4095)
    for (int w = tid; w < 896; w += 512) ((unsigned int*)As)[3200 + w] = 0u;
    // zero Hs pad rows 100..106 (903 dwords)
    for (int w = tid; w < 903; w += 512) ((unsigned int*)Hs)[12900 + w] = 0u;
    __syncthreads();

    // phase 1: H[128 rows][256 oc] = As . Wt^T ; wave = (rowblock rb, oc-quad oq)
    {
        const int rb = wv >> 2, oq = wv & 3;
        f32x4 acc[4][4] = {};
        #pragma unroll
        for (int ks = 0; ks < 2; ks++) {
            const unsigned short* wb = Wt + (oq * 64 + t) * 64 + q * 8 + ks * 32;
            bf16x8 bv[4], af[4];
            #pragma unroll
            for (int ni = 0; ni < 4; ni++) bv[ni] = *(const bf16x8*)(wb + ni * 1024);
            #pragma unroll
            for (int mi = 0; mi < 4; mi++) {
                int row = rb * 64 + mi * 16 + t;
                af[mi] = *(const bf16x8*)(As + row * 64 + (((ks * 4 + q) ^ (row & 7)) << 3));
            }
            #pragma unroll
            for (int mi = 0; mi < 4; mi++)
                #pragma unroll
                for (int ni = 0; ni < 4; ni++)
                    acc[mi][ni] = __builtin_amdgcn_mfma_f32_16x16x32_bf16(bv[ni], af[mi], acc[mi][ni], 0, 0, 0);
        }
        // epilogue: H -> Hs[row][oc] (u32-pair writes)
        #pragma unroll
        for (int mi = 0; mi < 4; mi++) {
            int row = rb * 64 + mi * 16 + t;
            if (row < 100) {
                #pragma unroll
                for (int ni = 0; ni < 4; ni++) {
                    int co = oq * 64 + ni * 16 + q * 4;
                    unsigned int* dst = (unsigned int*)(Hs + row * HS_STRIDE + co);
                    dst[0] = (unsigned int)f2bf(acc[mi][ni][0]) | ((unsigned int)f2bf(acc[mi][ni][1]) << 16);
                    dst[1] = (unsigned int)f2bf(acc[mi][ni][2]) | ((unsigned int)f2bf(acc[mi][ni][3]) << 16);
                }
            }
        }
    }
    __syncthreads();

    // phase 2: wave = (slab s, branch-half bh); i = bh*4+ii
    const int s = wv >> 1, bh = wv & 1;
    const bf16x8* AFp = (const bf16x8*)AF;
    const bf16x8 id0 = AFp[16 * 64 + ln];
    const bf16x8 id1 = AFp[17 * 64 + ln];
    f32x4 acc2[4][2];
    #pragma unroll
    for (int ii = 0; ii < 4; ii++) { acc2[ii][0] = (f32x4){0,0,0,0}; acc2[ii][1] = (f32x4){0,0,0,0}; }
    const int rowq = (s * 25 + q * 8) * HS_STRIDE + t;
    #pragma unroll
    for (int ii = 0; ii < 4; ii++) {
        const int i = bh * 4 + ii;
        unsigned short hm[8], hr[8];
        #pragma unroll
        for (int e = 0; e < 8; e++) {
            int a = rowq + e * HS_STRIDE + i * 16;
            hm[e] = Hs[a];
            hr[e] = Hs[a + 128];
        }
        bf16x8 bm = *(bf16x8*)hm;
        bf16x8 brs = *(bf16x8*)hr;
        bf16x8 a0 = AFp[(i * 2 + 0) * 64 + ln];
        bf16x8 a1 = AFp[(i * 2 + 1) * 64 + ln];
        acc2[ii][0] = __builtin_amdgcn_mfma_f32_16x16x32_bf16(id0, brs, acc2[ii][0], 0, 0, 0);
        acc2[ii][1] = __builtin_amdgcn_mfma_f32_16x16x32_bf16(id1, brs, acc2[ii][1], 0, 0, 0);
        acc2[ii][0] = __builtin_amdgcn_mfma_f32_16x16x32_bf16(a0, bm, acc2[ii][0], 0, 0, 0);
        acc2[ii][1] = __builtin_amdgcn_mfma_f32_16x16x32_bf16(a1, bm, acc2[ii][1], 0, 0, 0);
    }
    // per-o BN partials (k>=25 D slots are exact zeros); waves write disjoint (s, o-half)
    float* ps = (float*)SM;            // As region dead
    float* qs = ps + 512;
    #pragma unroll
    for (int ii = 0; ii < 4; ii++) {
        float si = 0.f, qi = 0.f;
        #pragma unroll
        for (int mt = 0; mt < 2; mt++)
            #pragma unroll
            for (int r = 0; r < 4; r++) {
                float v = acc2[ii][mt][r];
                si += v; qi += v * v;
            }
        si += __shfl_xor(si, 16); si += __shfl_xor(si, 32);
        qi += __shfl_xor(qi, 16); qi += __shfl_xor(qi, 32);
        if (ln < 16) {
            ps[s * 128 + (bh * 4 + ii) * 16 + t] = si;
            qs[s * 128 + (bh * 4 + ii) * 16 + t] = qi;
        }
    }
    // D -> own-slab Hs rows (own column half; disjoint from other waves' reads)
    #pragma unroll
    for (int ii = 0; ii < 4; ii++)
        #pragma unroll
        for (int mt = 0; mt < 2; mt++)
            #pragma unroll
            for (int r = 0; r < 4; r++) {
                int k = mt * 16 + q * 4 + r;
                if (k < 25)
                    Hs[(s * 25 + k) * HS_STRIDE + (bh * 4 + ii) * 16 + t] = f2bf(acc2[ii][mt][r]);
            }
    __syncthreads();
    if (tid < 128) {
        float S = ps[tid] + ps[128 + tid] + ps[256 + tid] + ps[384 + tid];
        float Q = qs[tid] + qs[128 + tid] + qs[256 + tid] + qs[384 + tid];
        int blk = b * 75 + tg;
        psc[(size_t)blk * 128 + tid] = S;
        psq[(size_t)blk * 128 + tid] = Q;
    }
    // Y write, linear [b*128+o][7500]: lane runs of 25 -> 200B-coalesced uint2 stores
    for (int idx = tid; idx < 3200; idx += 512) {
        int o = idx / 25, w = idx - o * 25;           // w = uint2 chunk (4 shorts)
        unsigned short vv[4];
        #pragma unroll
        for (int e = 0; e < 4; e++)
            vv[e] = Hs[(w * 4 + e) * HS_STRIDE + o];  // local row tk = s*25+k = w*4+e
        uint2 d;
        d.x = (unsigned int)vv[0] | ((unsigned int)vv[1] << 16);
        d.y = (unsigned int)vv[2] | ((unsigned int)vv[3] << 16);
        *(uint2*)(Yg + (size_t)(b * 128 + o) * TV + tg * 100 + w * 4) = d;
    }
}

// ---------------- merged stats reduce + BN finalize (128 blocks, one per o) ----
__global__ __launch_bounds__(256) void k_fin2(const float* __restrict__ psc,
                                              const float* __restrict__ psq,
                                              const float* __restrict__ gamma,
                                              const float* __restrict__ beta,
                                              float* __restrict__ scale,
                                              float* __restrict__ shift) {
    const int o = blockIdx.x, tid = threadIdx.x;
    float S = 0.f, Q = 0.f;
    for (int i = tid; i < NPF; i += 256) {
        S += psc[(size_t)i * 128 + o];
        Q += psq[(size_t)i * 128 + o];
    }
    #pragma unroll
    for (int m = 1; m < 64; m <<= 1) { S += __shfl_xor(S, m); Q += __shfl_xor(Q, m); }
    __shared__ float ls[4], lq[4];
    int w = tid >> 6;
    if ((tid & 63) == 0) { ls[w] = S; lq[w] = Q; }
    __syncthreads();
    if (tid == 0) {
        float St = ls[0] + ls[1] + ls[2] + ls[3];
        float Qt = lq[0] + lq[1] + lq[2] + lq[3];
        float inv = 1.f / (float)BTV;
        float mean = St * inv;
        float var = Qt * inv - mean * mean;
        float sc = gamma[o] / sqrtf(var + 1e-5f);
        scale[o] = sc;
        shift[o] = beta[o] - mean * sc;
    }
}

// ---------------- norm: Y[bo][7500] bf16 -> out f32, fully linear both sides ----
__global__ __launch_bounds__(256) void k_norm2(const unsigned short* __restrict__ Y,
                                               const float* __restrict__ scale,
                                               const float* __restrict__ shift,
                                               float* __restrict__ out) {
    size_t e0 = ((size_t)blockIdx.x * 256 + threadIdx.x) * 8;
    #pragma unroll
    for (int g = 0; g < 2; g++) {
        size_t e = e0 + (size_t)g * 4;
        int o = (int)((e / 7500) & 127);
        float sc = scale[o], sh = shift[o];
        uint2 v = *(const uint2*)(Y + e);
        float4 d;
        d.x = fmaxf(fmaf(bf2f((unsigned short)(v.x & 0xffffu)), sc, sh), 0.f);
        d.y = fmaxf(fmaf(bf2f((unsigned short)(v.x >> 16)),     sc, sh), 0.f);
        d.z = fmaxf(fmaf(bf2f((unsigned short)(v.y & 0xffffu)), sc, sh), 0.f);
        d.w = fmaxf(fmaf(bf2f((unsigned short)(v.y >> 16)),     sc, sh), 0.f);
        *(float4*)(out + e) = d;
    }
}

extern "C" void kernel_launch(void* const* d_in, const int* in_sizes, int n_in,
                              void* d_out, int out_size, void* d_ws, size_t ws_size,
                              hipStream_t stream) {
    const float* x     = (const float*)d_in[0];
    const float* A     = (const float*)d_in[1];
    const float* W     = (const float*)d_in[2];
    const float* Wr    = (const float*)d_in[3];
    const float* gamma = (const float*)d_in[5];
    const float* beta  = (const float*)d_in[6];
    float* out = (float*)d_out;
    char* wsb  = (char*)d_ws;
    if (ws_size < (size_t)WS_NEED2) return;

    unsigned short* AF  = (unsigned short*)(wsb + WSB_AF);
    unsigned short* Wt  = (unsigned short*)(wsb + WSB_WT);
    float*          psc = (float*)(wsb + WSB_PSC);
    float*          psq = (float*)(wsb + WSB_PSQ);
    float*          scl = (float*)(wsb + WSB_SCL);
    float*          sft = (float*)(wsb + WSB_SFT);
    unsigned short* Y   = (unsigned short*)(wsb + WSB_Y);

    k_prep<<<2, 256, 0, stream>>>(A, W, Wr, AF, Wt);
    k_fuse<<<dim3(75, 64), 512, 0, stream>>>(x, Wt, AF, Y, psc, psq);
    k_fin2<<<128, 256, 0, stream>>>(psc, psq, gamma, beta, scl, sft);
    k_norm2<<<30000, 256, 0, stream>>>(Y, scl, sft, out);
}

// Round 16
// 221.629 us; speedup vs baseline: 2.2729x; 1.0455x over previous
//
#include <hip/hip_runtime.h>
#include <hip/hip_bf16.h>

// Problem constants
#define B_  64
#define C_  64
#define T_  300
#define V_  25
#define O_  128
#define TV  (T_*V_)     // 7500
#define BTV (B_*T_*V_)  // 480000
#define HS_STRIDE 258   // LDS H row stride (shorts): conflict-free gather
#define HS_ROWS 107
#define NPF 4800        // 64 b x 75 tgroups (4 slabs each)

typedef __bf16 bf16x8 __attribute__((ext_vector_type(8)));
typedef float f32x4 __attribute__((ext_vector_type(4)));

// ---- ws layout (byte offsets) ----
#define WSB_AF    0ull           // A-fragment table [18][64][8] bf16 = 18432
#define WSB_WT    18432ull       // Wt[256][64] bf16 = 32768 -> 51200
#define WSB_PSC   51200ull       // [4800][128] f32
#define WSB_PSQ   2508800ull
#define WSB_P2C   4966400ull     // [96][128] f32
#define WSB_P2Q   5015552ull
#define WSB_SCL   5064704ull
#define WSB_SFT   5065216ull
#define WSB_Y     5065728ull     // [B*128][7500] bf16 = 122,880,000
#define WS_NEED2  127945728ull

static __device__ __forceinline__ unsigned short f2bf(float f) {
    unsigned int u = __float_as_uint(f);
    unsigned int r = (u + 0x7fffu + ((u >> 16) & 1u)) >> 16;
    return (unsigned short)r;
}
static __device__ __forceinline__ float bf2f(unsigned short u) {
    return __uint_as_float(((unsigned int)u) << 16);
}

// ---------------- prep: block 0 = A-power MFMA fragment table; block 1 = Wt ----
__global__ __launch_bounds__(256) void k_prep(const float* __restrict__ A,
                                              const float* __restrict__ W,
                                              const float* __restrict__ Wr,
                                              unsigned short* __restrict__ AF,
                                              unsigned short* __restrict__ Wt) {
    const int tid = threadIdx.x;
    if (blockIdx.x == 0) {
        __shared__ float Pall[8][625];
        for (int p = tid; p < 625; p += 256) Pall[0][p] = A[p];
        __syncthreads();
        for (int i = 1; i < 8; i++) {
            for (int p = tid; p < 625; p += 256) {
                int r = p / 25, c = p - r * 25;
                float s = 0.f;
                #pragma unroll 5
                for (int j = 0; j < 25; j++) s = fmaf(Pall[i-1][r*25 + j], A[j*25 + c], s);
                Pall[i][p] = s;
            }
            __syncthreads();
        }
        // AF[fi][lane][e]: fi<16: A^{i+1}[j][k], j=(l>>4)*8+e, k=(fi&1)*16+(l&15); fi=16,17: identity
        for (int idx = tid; idx < 18 * 64; idx += 256) {
            int fi = idx >> 6, l = idx & 63, qq = l >> 4, tt = l & 15;
            unsigned short v[8];
            #pragma unroll
            for (int e = 0; e < 8; e++) {
                int j = qq * 8 + e;
                float val = 0.f;
                if (fi < 16) {
                    int i = fi >> 1, k = (fi & 1) * 16 + tt;
                    if (j < 25 && k < 25) val = Pall[i][j * 25 + k];
                } else {
                    int k = (fi - 16) * 16 + tt;
                    if (j < 25 && k < 25 && j == k) val = 1.f;
                }
                v[e] = f2bf(val);
            }
            *(uint4*)(AF + idx * 8) = *(uint4*)v;
        }
    } else {
        const int oc = tid;
        const float* src = (oc < 128) ? (W + oc * 64) : (Wr + (oc - 128) * 64);
        unsigned short row[64];
        #pragma unroll
        for (int c = 0; c < 64; c++) row[c] = f2bf(src[c]);
        #pragma unroll
        for (int cc = 0; cc < 8; cc++)
            *(uint4*)(Wt + oc * 64 + cc * 8) = *(uint4*)(row + cc * 8);
    }
}

// ---------------- fused: x->H (MFMA) -> graph-apply (MFMA) + residual + BN + Y ----
// block: 512 thr (8 waves), 4 slabs (100 rows). 2 blocks/CU (71.6 KB LDS), 16 waves/CU.
__global__ __launch_bounds__(512, 2) void k_fuse(const float* __restrict__ x,
                                                 const unsigned short* __restrict__ Wt,
                                                 const unsigned short* __restrict__ AF,
                                                 unsigned short* __restrict__ Yg,
                                                 float* __restrict__ psc,
                                                 float* __restrict__ psq) {
    __shared__ __align__(16) unsigned short SM[8192 + HS_ROWS * HS_STRIDE];  // As | Hs
    unsigned short* As = SM;
    unsigned short* Hs = SM + 8192;
    const int tg = blockIdx.x, b = blockIdx.y;          // tg 0..74 (4 t-slabs)
    const int tid = threadIdx.x, wv = tid >> 6, ln = tid & 63;
    const int q = ln >> 4, t = ln & 15;

    // stage x -> As bf16 [row=tv_local(0..99)][c], chunk-XOR swizzled by row&7
    for (int p = tid; p < 1600; p += 512) {
        int c = p / 25, e4 = p - c * 25;
        float4 f = *(const float4*)(x + ((size_t)(b * 64 + c)) * TV + tg * 100 + e4 * 4);
        float vv[4] = { f.x, f.y, f.z, f.w };
        #pragma unroll
        for (int u = 0; u < 4; u++) {
            int r = e4 * 4 + u;
            As[r * 64 + (((c >> 3) ^ (r & 7)) << 3) + (c & 7)] = f2bf(vv[u]);
        }
    }
    // zero As pad rows 100..127 (dwords 3200..4095)
    for (int w = tid; w < 896; w += 512) ((unsigned int*)As)[3200 + w] = 0u;
    // zero Hs pad rows 100..106 (903 dwords)
    for (int w = tid; w < 903; w += 512) ((unsigned int*)Hs)[12900 + w] = 0u;
    __syncthreads();

    // phase 1: H[128 rows][256 oc] = As . Wt^T ; wave = (rowblock rb, oc-quad oq)
    {
        const int rb = wv >> 2, oq = wv & 3;
        f32x4 acc[4][4] = {};
        #pragma unroll
        for (int ks = 0; ks < 2; ks++) {
            const unsigned short* wb = Wt + (oq * 64 + t) * 64 + q * 8 + ks * 32;
            bf16x8 bv[4], af[4];
            #pragma unroll
            for (int ni = 0; ni < 4; ni++) bv[ni] = *(const bf16x8*)(wb + ni * 1024);
            #pragma unroll
            for (int mi = 0; mi < 4; mi++) {
                int row = rb * 64 + mi * 16 + t;
                af[mi] = *(const bf16x8*)(As + row * 64 + (((ks * 4 + q) ^ (row & 7)) << 3));
            }
            #pragma unroll
            for (int mi = 0; mi < 4; mi++)
                #pragma unroll
                for (int ni = 0; ni < 4; ni++)
                    acc[mi][ni] = __builtin_amdgcn_mfma_f32_16x16x32_bf16(bv[ni], af[mi], acc[mi][ni], 0, 0, 0);
        }
        // epilogue: H -> Hs[row][oc] (u32-pair writes)
        #pragma unroll
        for (int mi = 0; mi < 4; mi++) {
            int row = rb * 64 + mi * 16 + t;
            if (row < 100) {
                #pragma unroll
                for (int ni = 0; ni < 4; ni++) {
                    int co = oq * 64 + ni * 16 + q * 4;
                    unsigned int* dst = (unsigned int*)(Hs + row * HS_STRIDE + co);
                    dst[0] = (unsigned int)f2bf(acc[mi][ni][0]) | ((unsigned int)f2bf(acc[mi][ni][1]) << 16);
                    dst[1] = (unsigned int)f2bf(acc[mi][ni][2]) | ((unsigned int)f2bf(acc[mi][ni][3]) << 16);
                }
            }
        }
    }
    __syncthreads();

    // phase 2: wave = (slab s, branch-half bh); i = bh*4+ii
    const int s = wv >> 1, bh = wv & 1;
    const bf16x8* AFp = (const bf16x8*)AF;
    const bf16x8 id0 = AFp[16 * 64 + ln];
    const bf16x8 id1 = AFp[17 * 64 + ln];
    f32x4 acc2[4][2];
    #pragma unroll
    for (int ii = 0; ii < 4; ii++) { acc2[ii][0] = (f32x4){0,0,0,0}; acc2[ii][1] = (f32x4){0,0,0,0}; }
    const int rowq = (s * 25 + q * 8) * HS_STRIDE + t;
    #pragma unroll
    for (int ii = 0; ii < 4; ii++) {
        const int i = bh * 4 + ii;
        unsigned short hm[8], hr[8];
        #pragma unroll
        for (int e = 0; e < 8; e++) {
            int a = rowq + e * HS_STRIDE + i * 16;
            hm[e] = Hs[a];
            hr[e] = Hs[a + 128];
        }
        bf16x8 bm = *(bf16x8*)hm;
        bf16x8 brs = *(bf16x8*)hr;
        bf16x8 a0 = AFp[(i * 2 + 0) * 64 + ln];
        bf16x8 a1 = AFp[(i * 2 + 1) * 64 + ln];
        acc2[ii][0] = __builtin_amdgcn_mfma_f32_16x16x32_bf16(id0, brs, acc2[ii][0], 0, 0, 0);
        acc2[ii][1] = __builtin_amdgcn_mfma_f32_16x16x32_bf16(id1, brs, acc2[ii][1], 0, 0, 0);
        acc2[ii][0] = __builtin_amdgcn_mfma_f32_16x16x32_bf16(a0, bm, acc2[ii][0], 0, 0, 0);
        acc2[ii][1] = __builtin_amdgcn_mfma_f32_16x16x32_bf16(a1, bm, acc2[ii][1], 0, 0, 0);
    }
    // per-o BN partials (k>=25 D slots are exact zeros); waves write disjoint (s, o-half)
    float* ps = (float*)SM;            // As region dead
    float* qs = ps + 512;
    #pragma unroll
    for (int ii = 0; ii < 4; ii++) {
        float si = 0.f, qi = 0.f;
        #pragma unroll
        for (int mt = 0; mt < 2; mt++)
            #pragma unroll
            for (int r = 0; r < 4; r++) {
                float v = acc2[ii][mt][r];
                si += v; qi += v * v;
            }
        si += __shfl_xor(si, 16); si += __shfl_xor(si, 32);
        qi += __shfl_xor(qi, 16); qi += __shfl_xor(qi, 32);
        if (ln < 16) {
            ps[s * 128 + (bh * 4 + ii) * 16 + t] = si;
            qs[s * 128 + (bh * 4 + ii) * 16 + t] = qi;
        }
    }
    // D -> own-slab Hs rows (own column half; disjoint from other waves' reads)
    #pragma unroll
    for (int ii = 0; ii < 4; ii++)
        #pragma unroll
        for (int mt = 0; mt < 2; mt++)
            #pragma unroll
            for (int r = 0; r < 4; r++) {
                int k = mt * 16 + q * 4 + r;
                if (k < 25)
                    Hs[(s * 25 + k) * HS_STRIDE + (bh * 4 + ii) * 16 + t] = f2bf(acc2[ii][mt][r]);
            }
    __syncthreads();
    if (tid < 128) {
        float S = ps[tid] + ps[128 + tid] + ps[256 + tid] + ps[384 + tid];
        float Q = qs[tid] + qs[128 + tid] + qs[256 + tid] + qs[384 + tid];
        int blk = b * 75 + tg;
        psc[(size_t)blk * 128 + tid] = S;
        psq[(size_t)blk * 128 + tid] = Q;
    }
    // Y write, linear [b*128+o][7500]: lane runs of 25 -> 200B-coalesced uint2 stores
    for (int idx = tid; idx < 3200; idx += 512) {
        int o = idx / 25, w = idx - o * 25;           // w = uint2 chunk (4 shorts)
        unsigned short vv[4];
        #pragma unroll
        for (int e = 0; e < 4; e++)
            vv[e] = Hs[(w * 4 + e) * HS_STRIDE + o];  // local row tk = s*25+k = w*4+e
        uint2 d;
        d.x = (unsigned int)vv[0] | ((unsigned int)vv[1] << 16);
        d.y = (unsigned int)vv[2] | ((unsigned int)vv[3] << 16);
        *(uint2*)(Yg + (size_t)(b * 128 + o) * TV + tg * 100 + w * 4) = d;
    }
}

// ---------------- stage-1 reduction: 4800 -> 96 partials per o (row-coalesced) ----
__global__ __launch_bounds__(256) void k_red1(const float* __restrict__ psc,
                                              const float* __restrict__ psq,
                                              float* __restrict__ p2c,
                                              float* __restrict__ p2q) {
    const int r = blockIdx.x;              // 0..95, covers 50 blocks each
    const int tid = threadIdx.x;
    const int o = tid & 127;
    const float* src = (tid < 128) ? psc : psq;
    float* dst = (tid < 128) ? p2c : p2q;
    float S = 0.f;
    for (int ii = 0; ii < 50; ii++)
        S += src[(size_t)(r * 50 + ii) * 128 + o];
    dst[r * 128 + o] = S;
}

// ---------------- finalize BN ----------------
__global__ void k_fin(const float* __restrict__ p2c, const float* __restrict__ p2q,
                      const float* __restrict__ gamma, const float* __restrict__ beta,
                      float* __restrict__ scale, float* __restrict__ shift) {
    const int o = threadIdx.x;
    if (o >= 128) return;
    float S = 0.f, Q = 0.f;
    for (int r = 0; r < 96; r++) { S += p2c[r * 128 + o]; Q += p2q[r * 128 + o]; }
    float inv = 1.f / (float)BTV;
    float mean = S * inv;
    float var = Q * inv - mean * mean;
    float sc = gamma[o] / sqrtf(var + 1e-5f);
    scale[o] = sc;
    shift[o] = beta[o] - mean * sc;
}

// ---------------- norm: Y[bo][7500] bf16 -> out f32, fully linear both sides ----
__global__ __launch_bounds__(256) void k_norm2(const unsigned short* __restrict__ Y,
                                               const float* __restrict__ scale,
                                               const float* __restrict__ shift,
                                               float* __restrict__ out) {
    size_t e0 = ((size_t)blockIdx.x * 256 + threadIdx.x) * 8;
    #pragma unroll
    for (int g = 0; g < 2; g++) {
        size_t e = e0 + (size_t)g * 4;
        int o = (int)((e / 7500) & 127);
        float sc = scale[o], sh = shift[o];
        uint2 v = *(const uint2*)(Y + e);
        float4 d;
        d.x = fmaxf(fmaf(bf2f((unsigned short)(v.x & 0xffffu)), sc, sh), 0.f);
        d.y = fmaxf(fmaf(bf2f((unsigned short)(v.x >> 16)),     sc, sh), 0.f);
        d.z = fmaxf(fmaf(bf2f((unsigned short)(v.y & 0xffffu)), sc, sh), 0.f);
        d.w = fmaxf(fmaf(bf2f((unsigned short)(v.y >> 16)),     sc, sh), 0.f);
        *(float4*)(out + e) = d;
    }
}

extern "C" void kernel_launch(void* const* d_in, const int* in_sizes, int n_in,
                              void* d_out, int out_size, void* d_ws, size_t ws_size,
                              hipStream_t stream) {
    const float* x     = (const float*)d_in[0];
    const float* A     = (const float*)d_in[1];
    const float* W     = (const float*)d_in[2];
    const float* Wr    = (const float*)d_in[3];
    const float* gamma = (const float*)d_in[5];
    const float* beta  = (const float*)d_in[6];
    float* out = (float*)d_out;
    char* wsb  = (char*)d_ws;
    if (ws_size < (size_t)WS_NEED2) return;

    unsigned short* AF  = (unsigned short*)(wsb + WSB_AF);
    unsigned short* Wt  = (unsigned short*)(wsb + WSB_WT);
    float*          psc = (float*)(wsb + WSB_PSC);
    float*          psq = (float*)(wsb + WSB_PSQ);
    float*          p2c = (float*)(wsb + WSB_P2C);
    float*          p2q = (float*)(wsb + WSB_P2Q);
    float*          scl = (float*)(wsb + WSB_SCL);
    float*          sft = (float*)(wsb + WSB_SFT);
    unsigned short* Y   = (unsigned short*)(wsb + WSB_Y);

    k_prep<<<2, 256, 0, stream>>>(A, W, Wr, AF, Wt);
    k_fuse<<<dim3(75, 64), 512, 0, stream>>>(x, Wt, AF, Y, psc, psq);
    k_red1<<<96, 256, 0, stream>>>(psc, psq, p2c, p2q);
    k_fin<<<1, 128, 0, stream>>>(p2c, p2q, gamma, beta, scl, sft);
    k_norm2<<<30000, 256, 0, stream>>>(Y, scl, sft, out);
}